// Round 13
// baseline (3021.652 us; speedup 1.0000x reference)
//
#include <hip/hip_runtime.h>
#include <math.h>

__global__ __launch_bounds__(256) void fill_kernel(float* p, int n, float v) {
  int i = blockIdx.x * 256 + threadIdx.x;
  if (i < n) p[i] = v;
}

// ---------------- strict-fp32 BN apply (reference op order, unfolded)
// coef[c*5]: mr, mi, Rrr, Rii, Rri
__device__ __forceinline__ void bn_apply_f32(float xr, float xi,
                                             const float* __restrict__ cf,
                                             float grr, float gri, float gii,
                                             float bbr, float bbi, float& yr,
                                             float& yi) {
  float cr = __fsub_rn(xr, cf[0]);
  float ci = __fsub_rn(xi, cf[1]);
  float xhr = __fadd_rn(__fmul_rn(cf[2], cr), __fmul_rn(cf[4], ci));
  float xhi = __fadd_rn(__fmul_rn(cf[4], cr), __fmul_rn(cf[3], ci));
  yr = fmaxf(__fadd_rn(__fadd_rn(__fmul_rn(grr, xhr), __fmul_rn(gri, xhi)), bbr), 0.f);
  yi = fmaxf(__fadd_rn(__fadd_rn(__fmul_rn(gri, xhr), __fmul_rn(gii, xhi)), bbi), 0.f);
}

// 8 FMAs: two chains fed by one float4 read (v4), cin order ascending.
#define PFMA8(XX, YY, WV1, WV2) \
  XX = fmaf(v4.x, WV1.x, XX);   \
  XX = fmaf(v4.y, WV1.y, XX);   \
  XX = fmaf(v4.z, WV1.z, XX);   \
  XX = fmaf(v4.w, WV1.w, XX);   \
  YY = fmaf(v4.x, WV2.x, YY);   \
  YY = fmaf(v4.y, WV2.y, YY);   \
  YY = fmaf(v4.z, WV2.z, YY);   \
  YY = fmaf(v4.w, WV2.w, YY);

// ================= conv1 (cin=1, K=11) ====================================
#define C1_ROWBASE(pr) ((pr) * 84 + (((pr) >> 1) & 1))

template <int PASS>
__global__ __launch_bounds__(256, 2) void conv1_stats2(
    const float* __restrict__ x, const float* __restrict__ wr,
    const float* __restrict__ wi, const float* __restrict__ br,
    const float* __restrict__ bi, const float* __restrict__ coef,
    float* __restrict__ partial) {
  int b = blockIdx.x;
  int n = b >> 2, cg = b & 3;  // 4 channels per block
  int t = threadIdx.x;
  __shared__ __align__(16) float sx[74 * 84];
  __shared__ __align__(16) float4 swr4[121], swi4[121];  // [tap][ci]
  __shared__ float s0[256], s1[256], s2[PASS ? 256 : 1];

  for (int i = t; i < 74 * 84; i += 256) sx[i] = 0.f;
  for (int idx = t; idx < 484; idx += 256) {
    int wo = idx >> 2, ci = idx & 3;
    ((float*)swr4)[idx] = wr[(size_t)(cg * 4 + ci) * 121 + wo];
    ((float*)swi4)[idx] = wi[(size_t)(cg * 4 + ci) * 121 + wo];
  }
  __syncthreads();
  const float* xn = x + (size_t)n * 4096;
  for (int idx = t; idx < 1024; idx += 256) {
    float4 v = *(const float4*)(xn + idx * 4);
    int iy = idx >> 4, ixb = (idx & 15) * 4;
    int base = C1_ROWBASE(iy + 5) + ixb + 5;
    sx[base + 0] = v.x; sx[base + 1] = v.y;
    sx[base + 2] = v.z; sx[base + 3] = v.w;
  }
  __syncthreads();

  int leaf = t >> 3, j = t & 7;
  float a[4][16], bb[4][16];
#pragma unroll
  for (int ci = 0; ci < 4; ++ci)
#pragma unroll
    for (int k = 0; k < 16; ++k) { a[ci][k] = 0.f; bb[ci][k] = 0.f; }

  for (int ky = 0; ky < 11; ++ky) {
    int pr0 = leaf * 2 + ky;
    int base0 = C1_ROWBASE(pr0) + j;
    int base1 = C1_ROWBASE(pr0 + 1) + j;
    for (int kx = 0; kx < 11; ++kx) {
      const float* tb0 = sx + base0 + kx;
      const float* tb1 = sx + base1 + kx;
      float4 wR = swr4[ky * 11 + kx];
      float4 wI = swi4[ky * 11 + kx];
#pragma unroll
      for (int k8 = 0; k8 < 8; ++k8) {
        float v = tb0[k8 * 8];
        a[0][k8] = fmaf(v, wR.x, a[0][k8]);  bb[0][k8] = fmaf(v, wI.x, bb[0][k8]);
        a[1][k8] = fmaf(v, wR.y, a[1][k8]);  bb[1][k8] = fmaf(v, wI.y, bb[1][k8]);
        a[2][k8] = fmaf(v, wR.z, a[2][k8]);  bb[2][k8] = fmaf(v, wI.z, bb[2][k8]);
        a[3][k8] = fmaf(v, wR.w, a[3][k8]);  bb[3][k8] = fmaf(v, wI.w, bb[3][k8]);
      }
#pragma unroll
      for (int k8 = 0; k8 < 8; ++k8) {
        float v = tb1[k8 * 8];
        a[0][8 + k8] = fmaf(v, wR.x, a[0][8 + k8]);  bb[0][8 + k8] = fmaf(v, wI.x, bb[0][8 + k8]);
        a[1][8 + k8] = fmaf(v, wR.y, a[1][8 + k8]);  bb[1][8 + k8] = fmaf(v, wI.y, bb[1][8 + k8]);
        a[2][8 + k8] = fmaf(v, wR.z, a[2][8 + k8]);  bb[2][8 + k8] = fmaf(v, wI.z, bb[2][8 + k8]);
        a[3][8 + k8] = fmaf(v, wR.w, a[3][8 + k8]);  bb[3][8 + k8] = fmaf(v, wI.w, bb[3][8 + k8]);
      }
    }
  }

#pragma unroll
  for (int ci = 0; ci < 4; ++ci) {
    int c = cg * 4 + ci;
    float addR = __fsub_rn(br[c], bi[c]);
    float addI = __fadd_rn(br[c], bi[c]);
    float mr = 0.f, mi = 0.f;
    if (PASS) { mr = coef[c * 5 + 0]; mi = coef[c * 5 + 1]; }
    float a0 = 0.f, a1 = 0.f, a2 = 0.f;
#pragma unroll
    for (int k = 0; k < 16; ++k) {
      float xr = __fadd_rn(a[ci][k], addR);
      float xi = __fadd_rn(bb[ci][k], addI);
      if (PASS == 0) {
        a0 = __fadd_rn(a0, xr);
        a1 = __fadd_rn(a1, xi);
      } else {
        float cr = __fsub_rn(xr, mr), ci2 = __fsub_rn(xi, mi);
        a0 = __fadd_rn(a0, __fmul_rn(cr, cr));
        a1 = __fadd_rn(a1, __fmul_rn(ci2, ci2));
        a2 = __fadd_rn(a2, __fmul_rn(cr, ci2));
      }
    }
    s0[t] = a0; s1[t] = a1; if (PASS) s2[t] = a2;
    __syncthreads();
    if (t < 32) {
      int o = t * 8;
      float v0 = __fadd_rn(__fadd_rn(__fadd_rn(s0[o], s0[o + 1]), __fadd_rn(s0[o + 2], s0[o + 3])),
                           __fadd_rn(__fadd_rn(s0[o + 4], s0[o + 5]), __fadd_rn(s0[o + 6], s0[o + 7])));
      float v1 = __fadd_rn(__fadd_rn(__fadd_rn(s1[o], s1[o + 1]), __fadd_rn(s1[o + 2], s1[o + 3])),
                           __fadd_rn(__fadd_rn(s1[o + 4], s1[o + 5]), __fadd_rn(s1[o + 6], s1[o + 7])));
      float v2 = 0.f;
      if (PASS)
        v2 = __fadd_rn(__fadd_rn(__fadd_rn(s2[o], s2[o + 1]), __fadd_rn(s2[o + 2], s2[o + 3])),
                       __fadd_rn(__fadd_rn(s2[o + 4], s2[o + 5]), __fadd_rn(s2[o + 6], s2[o + 7])));
      s0[t] = v0; s1[t] = v1; if (PASS) s2[t] = v2;
    }
    if (t == 0) {
      for (int wdt = 32; wdt > 1; wdt >>= 1)
        for (int i = 0; i < (wdt >> 1); ++i) {
          s0[i] = __fadd_rn(s0[2 * i], s0[2 * i + 1]);
          s1[i] = __fadd_rn(s1[2 * i], s1[2 * i + 1]);
          if (PASS) s2[i] = __fadd_rn(s2[2 * i], s2[2 * i + 1]);
        }
      constexpr int S = PASS ? 3 : 2;
      size_t base = ((size_t)(n * 16 + c)) * S;
      partial[base + 0] = s0[0];
      partial[base + 1] = s1[0];
      if (PASS) partial[base + 2] = s2[0];
    }
    __syncthreads();
  }
}

__global__ __launch_bounds__(256, 2) void conv1_pool2(
    const float* __restrict__ x, const float* __restrict__ wr,
    const float* __restrict__ wi, const float* __restrict__ br,
    const float* __restrict__ bi, const float* __restrict__ coef,
    const float* __restrict__ grr, const float* __restrict__ gri,
    const float* __restrict__ gii, const float* __restrict__ bbr,
    const float* __restrict__ bbi, float* __restrict__ Pr,
    float* __restrict__ Pi) {
  int b = blockIdx.x;
  int n = b >> 2, cg = b & 3;
  int t = threadIdx.x;
  __shared__ __align__(16) float sx[74 * 84];
  __shared__ __align__(16) float4 swr4[121], swi4[121];

  for (int i = t; i < 74 * 84; i += 256) sx[i] = 0.f;
  for (int idx = t; idx < 484; idx += 256) {
    int wo = idx >> 2, ci = idx & 3;
    ((float*)swr4)[idx] = wr[(size_t)(cg * 4 + ci) * 121 + wo];
    ((float*)swi4)[idx] = wi[(size_t)(cg * 4 + ci) * 121 + wo];
  }
  __syncthreads();
  const float* xn = x + (size_t)n * 4096;
  for (int idx = t; idx < 1024; idx += 256) {
    float4 v = *(const float4*)(xn + idx * 4);
    int iy = idx >> 4, ixb = (idx & 15) * 4;
    int base = C1_ROWBASE(iy + 5) + ixb + 5;
    sx[base + 0] = v.x; sx[base + 1] = v.y;
    sx[base + 2] = v.z; sx[base + 3] = v.w;
  }
  __syncthreads();

  int oyb = t >> 5, ox = t & 31;
  float A[4][16], Bb[4][16];
#pragma unroll
  for (int ci = 0; ci < 4; ++ci)
#pragma unroll
    for (int e = 0; e < 16; ++e) { A[ci][e] = 0.f; Bb[ci][e] = 0.f; }

  for (int ky = 0; ky < 11; ++ky) {
    for (int kx = 0; kx < 11; ++kx) {
      float4 wR = swr4[ky * 11 + kx];
      float4 wI = swi4[ky * 11 + kx];
#pragma unroll
      for (int e = 0; e < 16; ++e) {
        int i = e >> 2, p = e & 3;
        int pr = 2 * (oyb + i * 8) + (p >> 1) + ky;
        int pc = 2 * ox + (p & 1) + kx;
        float v = sx[C1_ROWBASE(pr) + pc];
        A[0][e] = fmaf(v, wR.x, A[0][e]);  Bb[0][e] = fmaf(v, wI.x, Bb[0][e]);
        A[1][e] = fmaf(v, wR.y, A[1][e]);  Bb[1][e] = fmaf(v, wI.y, Bb[1][e]);
        A[2][e] = fmaf(v, wR.z, A[2][e]);  Bb[2][e] = fmaf(v, wI.z, Bb[2][e]);
        A[3][e] = fmaf(v, wR.w, A[3][e]);  Bb[3][e] = fmaf(v, wI.w, Bb[3][e]);
      }
    }
  }

#pragma unroll
  for (int ci = 0; ci < 4; ++ci) {
    int c = cg * 4 + ci;
    float addR = __fsub_rn(br[c], bi[c]);
    float addI = __fadd_rn(br[c], bi[c]);
    const float* cf = coef + c * 5;
    float gR = grr[c], gI = gri[c], gG = gii[c], bR = bbr[c], bI2 = bbi[c];
#pragma unroll
    for (int i = 0; i < 4; ++i) {
      int oy = oyb + i * 8;
      float bestr = 0.f, besti = 0.f, bestm = -1.f;
#pragma unroll
      for (int p = 0; p < 4; ++p) {
        float xr = __fadd_rn(A[ci][i * 4 + p], addR);
        float xi = __fadd_rn(Bb[ci][i * 4 + p], addI);
        float yr, yi;
        bn_apply_f32(xr, xi, cf, gR, gI, gG, bR, bI2, yr, yi);
        float m = __fadd_rn(__fmul_rn(yr, yr), __fmul_rn(yi, yi));
        if (m > bestm) { bestm = m; bestr = yr; besti = yi; }
      }
      size_t o = ((size_t)(n * 16 + c) * 32 + oy) * 32 + ox;
      Pr[o] = bestr;
      Pi[o] = besti;
    }
  }
}

// conv1 store-once: same conv chains as conv1_stats2, writes per-pixel
// (xr, xi) post-bias to buf[n][cl][4096] for 8 channels (2 cg blocks/group).
// Chains bit-identical (ky->kx fmaf, zero-padded tile).
__global__ __launch_bounds__(256, 2) void conv1_store(
    const float* __restrict__ x, const float* __restrict__ wr,
    const float* __restrict__ wi, const float* __restrict__ br,
    const float* __restrict__ bi, int cgoff, float* __restrict__ bufR,
    float* __restrict__ bufI) {
  int b = blockIdx.x;
  int n = b >> 1, cgl = b & 1;
  int cg = cgoff + cgl;
  int t = threadIdx.x;
  __shared__ __align__(16) float sx[74 * 84];
  __shared__ __align__(16) float4 swr4[121], swi4[121];

  for (int i = t; i < 74 * 84; i += 256) sx[i] = 0.f;
  for (int idx = t; idx < 484; idx += 256) {
    int wo = idx >> 2, ci = idx & 3;
    ((float*)swr4)[idx] = wr[(size_t)(cg * 4 + ci) * 121 + wo];
    ((float*)swi4)[idx] = wi[(size_t)(cg * 4 + ci) * 121 + wo];
  }
  __syncthreads();
  const float* xn = x + (size_t)n * 4096;
  for (int idx = t; idx < 1024; idx += 256) {
    float4 v = *(const float4*)(xn + idx * 4);
    int iy = idx >> 4, ixb = (idx & 15) * 4;
    int base = C1_ROWBASE(iy + 5) + ixb + 5;
    sx[base + 0] = v.x; sx[base + 1] = v.y;
    sx[base + 2] = v.z; sx[base + 3] = v.w;
  }
  __syncthreads();

  int leaf = t >> 3, j = t & 7;
  float a[4][16], bb[4][16];
#pragma unroll
  for (int ci = 0; ci < 4; ++ci)
#pragma unroll
    for (int k = 0; k < 16; ++k) { a[ci][k] = 0.f; bb[ci][k] = 0.f; }

  for (int ky = 0; ky < 11; ++ky) {
    int pr0 = leaf * 2 + ky;
    int base0 = C1_ROWBASE(pr0) + j;
    int base1 = C1_ROWBASE(pr0 + 1) + j;
    for (int kx = 0; kx < 11; ++kx) {
      const float* tb0 = sx + base0 + kx;
      const float* tb1 = sx + base1 + kx;
      float4 wR = swr4[ky * 11 + kx];
      float4 wI = swi4[ky * 11 + kx];
#pragma unroll
      for (int k8 = 0; k8 < 8; ++k8) {
        float v = tb0[k8 * 8];
        a[0][k8] = fmaf(v, wR.x, a[0][k8]);  bb[0][k8] = fmaf(v, wI.x, bb[0][k8]);
        a[1][k8] = fmaf(v, wR.y, a[1][k8]);  bb[1][k8] = fmaf(v, wI.y, bb[1][k8]);
        a[2][k8] = fmaf(v, wR.z, a[2][k8]);  bb[2][k8] = fmaf(v, wI.z, bb[2][k8]);
        a[3][k8] = fmaf(v, wR.w, a[3][k8]);  bb[3][k8] = fmaf(v, wI.w, bb[3][k8]);
      }
#pragma unroll
      for (int k8 = 0; k8 < 8; ++k8) {
        float v = tb1[k8 * 8];
        a[0][8 + k8] = fmaf(v, wR.x, a[0][8 + k8]);  bb[0][8 + k8] = fmaf(v, wI.x, bb[0][8 + k8]);
        a[1][8 + k8] = fmaf(v, wR.y, a[1][8 + k8]);  bb[1][8 + k8] = fmaf(v, wI.y, bb[1][8 + k8]);
        a[2][8 + k8] = fmaf(v, wR.z, a[2][8 + k8]);  bb[2][8 + k8] = fmaf(v, wI.z, bb[2][8 + k8]);
        a[3][8 + k8] = fmaf(v, wR.w, a[3][8 + k8]);  bb[3][8 + k8] = fmaf(v, wI.w, bb[3][8 + k8]);
      }
    }
  }

#pragma unroll
  for (int ci = 0; ci < 4; ++ci) {
    int c = cg * 4 + ci;
    float addR = __fsub_rn(br[c], bi[c]);
    float addI = __fadd_rn(br[c], bi[c]);
    int cl = cgl * 4 + ci;
    size_t base = ((size_t)n * 8 + cl) * 4096;
#pragma unroll
    for (int k = 0; k < 16; ++k) {
      int px = leaf * 128 + k * 8 + j;
      bufR[base + px] = __fadd_rn(a[ci][k], addR);
      bufI[base + px] = __fadd_rn(bb[ci][k], addI);
    }
  }
}

// ---- weight repack: [co][ci][kk] -> [co][kk][ci] (for float4 cin loads)
__global__ __launch_bounds__(256) void repack_w(const float* __restrict__ src,
                                                float* __restrict__ dst,
                                                int CIN, int KK, int total) {
  int i = blockIdx.x * 256 + threadIdx.x;
  if (i >= total) return;
  int kk = i % KK;
  int rem = i / KK;
  int ci = rem % CIN;
  int co = rem / CIN;
  dst[((size_t)co * KK + kk) * CIN + ci] = src[i];
}

// ---- generic transpose: src[R][C] -> dst[C][R]
__global__ __launch_bounds__(256) void transpose_rc(const float* __restrict__ src,
                                                    float* __restrict__ dst,
                                                    int R, int C) {
  int i = blockIdx.x * 256 + threadIdx.x;
  if (i >= R * C) return;
  int r = i / C, c = i % C;
  dst[(size_t)c * R + r] = src[i];
}

// ============== band kernels (fallback L2 path) ===========================
#define STAGE_COMP(SRCBASE)                                          \
  {                                                                  \
    const float* src_ = (SRCBASE) + (size_t)n * CIN * HH;            \
    for (int idx = t; idx < RALLOC * H * CINQ; idx += NT) {          \
      int px = idx % (RALLOC * H);                                   \
      int cq = idx / (RALLOC * H);                                   \
      int lr = px / H, col = px - lr * H;                            \
      int gr = r0 + lr;                                              \
      if (gr < 0 || gr >= H) continue;                               \
      const float* sp = src_ + (size_t)cq * 4 * HH + gr * H + col;   \
      float4 v;                                                      \
      v.x = sp[0]; v.y = sp[HH]; v.z = sp[2 * HH]; v.w = sp[3 * HH]; \
      *(float4*)&sin_[(lr * W + col + PAD) * ST1 + cq * 4] = v;      \
    }                                                                \
  }

template <int H, int CIN, int COUT, int K, int PASS>
__global__ __launch_bounds__(COUT * 4, 2) void cconv_band_stats(
    const float* __restrict__ Xr, const float* __restrict__ Xi,
    const float* __restrict__ wrT, const float* __restrict__ wiT,
    const float* __restrict__ br, const float* __restrict__ bi,
    const float* __restrict__ coef, float* __restrict__ partial) {
  constexpr int HH = H * H;
  constexpr int PAD = K / 2, KK = K * K;
  constexpr int CLEN = (HH >= 128) ? 16 : 8;
  constexpr int NLEAF = HH / (8 * CLEN);
  constexpr int BROWS = (CLEN * 8) / H;
  constexpr int RALLOC = BROWS + 2 * PAD;
  constexpr int W = H + 2 * PAD;
  constexpr int ST1 = CIN + 4;
  constexpr int CINQ = CIN / 4;
  constexpr int NT = COUT * 4;
  constexpr int NC = COUT * 8;

  __shared__ __align__(16) float sin_[RALLOC * W * ST1];
  __shared__ float red0[NC], red1[NC], red2[PASS ? NC : 1];

  int b = blockIdx.x;
  int leaf = b % NLEAF;
  int n = b / NLEAF;
  int t = threadIdx.x;
  int r0 = leaf * BROWS - PAD;

  for (int i = t; i < RALLOC * W * ST1; i += NT) sin_[i] = 0.f;
  __syncthreads();
  STAGE_COMP(Xr)
  __syncthreads();

  int c0 = t >> 3, j = t & 7;
  int c1 = c0 + COUT / 2;
  const float* wrb0 = wrT + (size_t)c0 * CIN * KK;
  const float* wib0 = wiT + (size_t)c0 * CIN * KK;
  const float* wrb1 = wrT + (size_t)c1 * CIN * KK;
  const float* wib1 = wiT + (size_t)c1 * CIN * KK;

  float A0[CLEN], D0[CLEN], A1[CLEN], D1[CLEN];
  float B0[CLEN], C0_[CLEN], B1[CLEN], C1_[CLEN];
#pragma unroll
  for (int k = 0; k < CLEN; ++k) {
    A0[k] = 0.f; D0[k] = 0.f; A1[k] = 0.f; D1[k] = 0.f;
    B0[k] = 0.f; C0_[k] = 0.f; B1[k] = 0.f; C1_[k] = 0.f;
  }

#define STATS_TAPS(PH)                                                        \
  for (int ky = 0; ky < K; ++ky) {                                            \
    for (int kx = 0; kx < K; ++kx) {                                          \
      const float* tb = sin_ + (ky * W + kx + j) * ST1;                       \
      const float* wrp0 = wrb0 + (ky * K + kx) * CIN;                         \
      const float* wip0 = wib0 + (ky * K + kx) * CIN;                         \
      const float* wrp1 = wrb1 + (ky * K + kx) * CIN;                         \
      const float* wip1 = wib1 + (ky * K + kx) * CIN;                         \
      _Pragma("unroll 2") for (int cq = 0; cq < CINQ; ++cq) {                 \
        const float* tbc = tb + cq * 4;                                       \
        float4 wR0v = *(const float4*)(wrp0 + cq * 4);                        \
        float4 wI0v = *(const float4*)(wip0 + cq * 4);                        \
        float4 wR1v = *(const float4*)(wrp1 + cq * 4);                        \
        float4 wI1v = *(const float4*)(wip1 + cq * 4);                        \
        _Pragma("unroll") for (int k = 0; k < CLEN; ++k) {                    \
          float4 v4 = *(const float4*)(tbc +                                  \
              (((k * 8) / H) * W + ((k * 8) % H)) * ST1);                     \
          if (PH == 0) {                                                      \
            PFMA8(A0[k], D0[k], wR0v, wI0v)                                   \
            PFMA8(A1[k], D1[k], wR1v, wI1v)                                   \
          } else {                                                            \
            PFMA8(B0[k], C0_[k], wI0v, wR0v)                                  \
            PFMA8(B1[k], C1_[k], wI1v, wR1v)                                  \
          }                                                                   \
        }                                                                     \
      }                                                                       \
    }                                                                         \
  }

  STATS_TAPS(0)
  __syncthreads();
  STAGE_COMP(Xi)
  __syncthreads();
  STATS_TAPS(1)
#undef STATS_TAPS

  {  // c0 epilogue
    float cbR = br[c0], cbI = bi[c0];
    float mr = 0.f, mi = 0.f;
    if (PASS) { mr = coef[c0 * 5 + 0]; mi = coef[c0 * 5 + 1]; }
    float a0 = 0.f, a1 = 0.f, a2 = 0.f;
#pragma unroll
    for (int k = 0; k < CLEN; ++k) {
      float yr = __fsub_rn(__fadd_rn(A0[k], cbR), __fadd_rn(B0[k], cbI));
      float yi = __fadd_rn(__fadd_rn(C0_[k], cbR), __fadd_rn(D0[k], cbI));
      if (PASS == 0) {
        a0 = __fadd_rn(a0, yr);
        a1 = __fadd_rn(a1, yi);
      } else {
        float cr = __fsub_rn(yr, mr), ci = __fsub_rn(yi, mi);
        a0 = __fadd_rn(a0, __fmul_rn(cr, cr));
        a1 = __fadd_rn(a1, __fmul_rn(ci, ci));
        a2 = __fadd_rn(a2, __fmul_rn(cr, ci));
      }
    }
    red0[c0 * 8 + j] = a0; red1[c0 * 8 + j] = a1;
    if (PASS) red2[c0 * 8 + j] = a2;
  }
  {  // c1 epilogue
    float cbR = br[c1], cbI = bi[c1];
    float mr = 0.f, mi = 0.f;
    if (PASS) { mr = coef[c1 * 5 + 0]; mi = coef[c1 * 5 + 1]; }
    float a0 = 0.f, a1 = 0.f, a2 = 0.f;
#pragma unroll
    for (int k = 0; k < CLEN; ++k) {
      float yr = __fsub_rn(__fadd_rn(A1[k], cbR), __fadd_rn(B1[k], cbI));
      float yi = __fadd_rn(__fadd_rn(C1_[k], cbR), __fadd_rn(D1[k], cbI));
      if (PASS == 0) {
        a0 = __fadd_rn(a0, yr);
        a1 = __fadd_rn(a1, yi);
      } else {
        float cr = __fsub_rn(yr, mr), ci = __fsub_rn(yi, mi);
        a0 = __fadd_rn(a0, __fmul_rn(cr, cr));
        a1 = __fadd_rn(a1, __fmul_rn(ci, ci));
        a2 = __fadd_rn(a2, __fmul_rn(cr, ci));
      }
    }
    red0[c1 * 8 + j] = a0; red1[c1 * 8 + j] = a1;
    if (PASS) red2[c1 * 8 + j] = a2;
  }
  __syncthreads();
  if (j == 0) {
    constexpr int S = PASS ? 3 : 2;
#pragma unroll
    for (int s = 0; s < 2; ++s) {
      int cc = s ? c1 : c0;
      int o = cc * 8;
      size_t base = (((size_t)n * COUT + cc) * NLEAF + leaf) * S;
      partial[base + 0] =
          __fadd_rn(__fadd_rn(__fadd_rn(red0[o], red0[o + 1]), __fadd_rn(red0[o + 2], red0[o + 3])),
                    __fadd_rn(__fadd_rn(red0[o + 4], red0[o + 5]), __fadd_rn(red0[o + 6], red0[o + 7])));
      partial[base + 1] =
          __fadd_rn(__fadd_rn(__fadd_rn(red1[o], red1[o + 1]), __fadd_rn(red1[o + 2], red1[o + 3])),
                    __fadd_rn(__fadd_rn(red1[o + 4], red1[o + 5]), __fadd_rn(red1[o + 6], red1[o + 7])));
      if (PASS)
        partial[base + 2] =
            __fadd_rn(__fadd_rn(__fadd_rn(red2[o], red2[o + 1]), __fadd_rn(red2[o + 2], red2[o + 3])),
                      __fadd_rn(__fadd_rn(red2[o + 4], red2[o + 5]), __fadd_rn(red2[o + 6], red2[o + 7])));
    }
  }
}

template <int H, int CIN, int COUT, int K, int OBR>
__global__ __launch_bounds__(COUT * 4, 2) void cconv_band_pool(
    const float* __restrict__ Xr, const float* __restrict__ Xi,
    const float* __restrict__ wrT, const float* __restrict__ wiT,
    const float* __restrict__ br, const float* __restrict__ bi,
    const float* __restrict__ coef, const float* __restrict__ grr,
    const float* __restrict__ gri, const float* __restrict__ gii,
    const float* __restrict__ bbr, const float* __restrict__ bbi,
    float* __restrict__ Pr, float* __restrict__ Pi) {
  constexpr int HH = H * H;
  constexpr int OH = H / 2;
  constexpr int NBAND = OH / OBR;
  constexpr int PAD = K / 2, KK = K * K;
  constexpr int CROWS = OBR * 2;
  constexpr int RALLOC = CROWS + 2 * PAD;
  constexpr int W = H + 2 * PAD;
  constexpr int ST1 = CIN + 4;
  constexpr int CINQ = CIN / 4;
  constexpr int NT = COUT * 4;
  constexpr int NOUT = (OBR * OH) / 8;
  constexpr int NQ = NOUT * 4;

  __shared__ __align__(16) float sin_[RALLOC * W * ST1];

  int b = blockIdx.x;
  int band = b % NBAND;
  int n = b / NBAND;
  int t = threadIdx.x;
  int r0 = band * CROWS - PAD;

  for (int i = t; i < RALLOC * W * ST1; i += NT) sin_[i] = 0.f;
  __syncthreads();
  STAGE_COMP(Xr)
  __syncthreads();

  int c0 = t >> 3, j = t & 7;
  int c1 = c0 + COUT / 2;
  const float* jbp = sin_ + (2 * (j / OH) * W + 2 * (j % OH)) * ST1;
  const float* wrb0 = wrT + (size_t)c0 * CIN * KK;
  const float* wib0 = wiT + (size_t)c0 * CIN * KK;
  const float* wrb1 = wrT + (size_t)c1 * CIN * KK;
  const float* wib1 = wiT + (size_t)c1 * CIN * KK;

  float A0[NQ], D0[NQ], A1[NQ], D1[NQ];
  float B0[NQ], C0_[NQ], B1[NQ], C1_[NQ];
#pragma unroll
  for (int q = 0; q < NQ; ++q) {
    A0[q] = 0.f; D0[q] = 0.f; A1[q] = 0.f; D1[q] = 0.f;
    B0[q] = 0.f; C0_[q] = 0.f; B1[q] = 0.f; C1_[q] = 0.f;
  }

#define POOL_TAPS(PH)                                                         \
  for (int ky = 0; ky < K; ++ky) {                                            \
    for (int kx = 0; kx < K; ++kx) {                                          \
      const float* tb = jbp + (ky * W + kx) * ST1;                            \
      const float* wrp0 = wrb0 + (ky * K + kx) * CIN;                         \
      const float* wip0 = wib0 + (ky * K + kx) * CIN;                         \
      const float* wrp1 = wrb1 + (ky * K + kx) * CIN;                         \
      const float* wip1 = wib1 + (ky * K + kx) * CIN;                         \
      _Pragma("unroll 2") for (int cq = 0; cq < CINQ; ++cq) {                 \
        const float* tbc = tb + cq * 4;                                       \
        float4 wR0v = *(const float4*)(wrp0 + cq * 4);                        \
        float4 wI0v = *(const float4*)(wip0 + cq * 4);                        \
        float4 wR1v = *(const float4*)(wrp1 + cq * 4);                        \
        float4 wI1v = *(const float4*)(wip1 + cq * 4);                        \
        _Pragma("unroll") for (int q = 0; q < NQ; ++q) {                      \
          float4 v4 = *(const float4*)(tbc +                                  \
              ((2 * ((8 * (q >> 2)) / OH) + ((q & 3) >> 1)) * W +             \
               2 * ((8 * (q >> 2)) % OH) + ((q & 3) & 1)) * ST1);             \
          if (PH == 0) {                                                      \
            PFMA8(A0[q], D0[q], wR0v, wI0v)                                   \
            PFMA8(A1[q], D1[q], wR1v, wI1v)                                   \
          } else {                                                            \
            PFMA8(B0[q], C0_[q], wI0v, wR0v)                                  \
            PFMA8(B1[q], C1_[q], wI1v, wR1v)                                  \
          }                                                                   \
        }                                                                     \
      }                                                                       \
    }                                                                         \
  }

  POOL_TAPS(0)
  __syncthreads();
  STAGE_COMP(Xi)
  __syncthreads();
  POOL_TAPS(1)
#undef POOL_TAPS

  {  // c0 epilogue
    float cbR = br[c0], cbI = bi[c0];
    const float* cf = coef + c0 * 5;
    float gR = grr[c0], gI = gri[c0], gG = gii[c0], bR = bbr[c0], bI2 = bbi[c0];
#pragma unroll
    for (int u = 0; u < NOUT; ++u) {
      int e = j + 8 * u;
      int oy = band * OBR + e / OH, ox = e % OH;
      float bestr = 0.f, besti = 0.f, bestm = -1.f;
#pragma unroll
      for (int p = 0; p < 4; ++p) {
        int q = u * 4 + p;
        float xr = __fsub_rn(__fadd_rn(A0[q], cbR), __fadd_rn(B0[q], cbI));
        float xi = __fadd_rn(__fadd_rn(C0_[q], cbR), __fadd_rn(D0[q], cbI));
        float yr, yi;
        bn_apply_f32(xr, xi, cf, gR, gI, gG, bR, bI2, yr, yi);
        float m = __fadd_rn(__fmul_rn(yr, yr), __fmul_rn(yi, yi));
        if (m > bestm) { bestm = m; bestr = yr; besti = yi; }
      }
      size_t o = ((size_t)(n * COUT + c0) * OH + oy) * OH + ox;
      Pr[o] = bestr;
      Pi[o] = besti;
    }
  }
  {  // c1 epilogue
    float cbR = br[c1], cbI = bi[c1];
    const float* cf = coef + c1 * 5;
    float gR = grr[c1], gI = gri[c1], gG = gii[c1], bR = bbr[c1], bI2 = bbi[c1];
#pragma unroll
    for (int u = 0; u < NOUT; ++u) {
      int e = j + 8 * u;
      int oy = band * OBR + e / OH, ox = e % OH;
      float bestr = 0.f, besti = 0.f, bestm = -1.f;
#pragma unroll
      for (int p = 0; p < 4; ++p) {
        int q = u * 4 + p;
        float xr = __fsub_rn(__fadd_rn(A1[q], cbR), __fadd_rn(B1[q], cbI));
        float xi = __fadd_rn(__fadd_rn(C1_[q], cbR), __fadd_rn(D1[q], cbI));
        float yr, yi;
        bn_apply_f32(xr, xi, cf, gR, gI, gG, bR, bI2, yr, yi);
        float m = __fadd_rn(__fmul_rn(yr, yr), __fmul_rn(yi, yi));
        if (m > bestm) { bestm = m; bestr = yr; besti = yi; }
      }
      size_t o = ((size_t)(n * COUT + c1) * OH + oy) * OH + ox;
      Pr[o] = bestr;
      Pi[o] = besti;
    }
  }
}

// ============== store-once path: conv -> buf, then stream passes ===========
// 2-channel store (used for the big L2 store and NEED2 fallback tier).
template <int H, int CIN, int COUT, int CG, int K, int REPS>
__global__ __launch_bounds__((CG / 2) * 8 * REPS, 2) void cconv_band_store(
    const float* __restrict__ Xr, const float* __restrict__ Xi,
    const float* __restrict__ wrT, const float* __restrict__ wiT,
    const float* __restrict__ br, const float* __restrict__ bi,
    int coff, float* __restrict__ bufR, float* __restrict__ bufI) {
  constexpr int HH = H * H;
  constexpr int PAD = K / 2, KK = K * K;
  constexpr int CLEN = (HH >= 128) ? 16 : 8;
  constexpr int NLEAF = HH / (8 * CLEN);
  constexpr int BROWS = (CLEN * 8) / H;
  constexpr int RALLOC = BROWS + 2 * PAD;
  constexpr int W = H + 2 * PAD;
  constexpr int ST1 = CIN + 4;
  constexpr int CINQ = CIN / 4;
  constexpr int CPAIR = CG / 2;
  constexpr int NT = CPAIR * 8 * REPS;
  constexpr int CLT = CLEN / REPS;           // k per thread
  constexpr int RROWS = (CLT * 8) / H;       // rows per replica (REPS>1)

  __shared__ __align__(16) float sin_[RALLOC * W * ST1];

  int b = blockIdx.x;
  int leaf = b % NLEAF;
  int n = b / NLEAF;
  int t = threadIdx.x;
  int r0 = leaf * BROWS - PAD;

  for (int i = t; i < RALLOC * W * ST1; i += NT) sin_[i] = 0.f;
  __syncthreads();
  STAGE_COMP(Xr)
  __syncthreads();

  int rep = t / (CPAIR * 8);
  int tt = t % (CPAIR * 8);
  int c0l = tt >> 3, j = tt & 7;
  int c0 = coff + c0l, c1 = c0 + CPAIR;
  const float* jbp = sin_ + ((REPS > 1 ? rep * RROWS : 0) * W + j) * ST1;
  const float* wrb0 = wrT + (size_t)c0 * CIN * KK;
  const float* wib0 = wiT + (size_t)c0 * CIN * KK;
  const float* wrb1 = wrT + (size_t)c1 * CIN * KK;
  const float* wib1 = wiT + (size_t)c1 * CIN * KK;

  float A0[CLT], D0[CLT], A1[CLT], D1[CLT];
  float B0[CLT], C0_[CLT], B1[CLT], C1_[CLT];
#pragma unroll
  for (int k = 0; k < CLT; ++k) {
    A0[k] = 0.f; D0[k] = 0.f; A1[k] = 0.f; D1[k] = 0.f;
    B0[k] = 0.f; C0_[k] = 0.f; B1[k] = 0.f; C1_[k] = 0.f;
  }

#define STORE_TAPS(PH)                                                        \
  for (int ky = 0; ky < K; ++ky) {                                            \
    for (int kx = 0; kx < K; ++kx) {                                          \
      const float* tb = jbp + (ky * W + kx) * ST1;                            \
      const float* wrp0 = wrb0 + (ky * K + kx) * CIN;                         \
      const float* wip0 = wib0 + (ky * K + kx) * CIN;                         \
      const float* wrp1 = wrb1 + (ky * K + kx) * CIN;                         \
      const float* wip1 = wib1 + (ky * K + kx) * CIN;                         \
      _Pragma("unroll 2") for (int cq = 0; cq < CINQ; ++cq) {                 \
        const float* tbc = tb + cq * 4;                                       \
        float4 wR0v = *(const float4*)(wrp0 + cq * 4);                        \
        float4 wI0v = *(const float4*)(wip0 + cq * 4);                        \
        float4 wR1v = *(const float4*)(wrp1 + cq * 4);                        \
        float4 wI1v = *(const float4*)(wip1 + cq * 4);                        \
        _Pragma("unroll") for (int k = 0; k < CLT; ++k) {                     \
          float4 v4 = *(const float4*)(tbc +                                  \
              (((k * 8) / H) * W + ((k * 8) % H)) * ST1);                     \
          if (PH == 0) {                                                      \
            PFMA8(A0[k], D0[k], wR0v, wI0v)                                   \
            PFMA8(A1[k], D1[k], wR1v, wI1v)                                   \
          } else {                                                            \
            PFMA8(B0[k], C0_[k], wI0v, wR0v)                                  \
            PFMA8(B1[k], C1_[k], wI1v, wR1v)                                  \
          }                                                                   \
        }                                                                     \
      }                                                                       \
    }                                                                         \
  }

  STORE_TAPS(0)
  __syncthreads();
  STAGE_COMP(Xi)
  __syncthreads();
  STORE_TAPS(1)
#undef STORE_TAPS

  float cbR0 = br[c0], cbI0 = bi[c0];
  float cbR1 = br[c1], cbI1 = bi[c1];
  size_t b0 = ((size_t)n * CG + c0l) * HH;
  size_t b1 = ((size_t)n * CG + (c0l + CPAIR)) * HH;
#pragma unroll
  for (int k = 0; k < CLT; ++k) {
    int px = leaf * CLEN * 8 + (rep * CLT + k) * 8 + j;
    float yr0 = __fsub_rn(__fadd_rn(A0[k], cbR0), __fadd_rn(B0[k], cbI0));
    float yi0 = __fadd_rn(__fadd_rn(C0_[k], cbR0), __fadd_rn(D0[k], cbI0));
    bufR[b0 + px] = yr0;
    bufI[b0 + px] = yi0;
    float yr1 = __fsub_rn(__fadd_rn(A1[k], cbR1), __fadd_rn(B1[k], cbI1));
    float yi1 = __fadd_rn(__fadd_rn(C1_[k], cbR1), __fadd_rn(D1[k], cbI1));
    bufR[b1 + px] = yr1;
    bufI[b1 + px] = yi1;
  }
}

// 4-channel store (L3/L4 where K=3 makes weight reload cheap).
template <int H, int CIN, int COUT, int CG, int K, int REPS>
__global__ __launch_bounds__((CG / 4) * 8 * REPS, 2) void cconv_band_store4(
    const float* __restrict__ Xr, const float* __restrict__ Xi,
    const float* __restrict__ wrT, const float* __restrict__ wiT,
    const float* __restrict__ br, const float* __restrict__ bi,
    int coff, float* __restrict__ bufR, float* __restrict__ bufI) {
  constexpr int HH = H * H;
  constexpr int PAD = K / 2, KK = K * K;
  constexpr int CLEN = (HH >= 128) ? 16 : 8;
  constexpr int NLEAF = HH / (8 * CLEN);
  constexpr int BROWS = (CLEN * 8) / H;
  constexpr int RALLOC = BROWS + 2 * PAD;
  constexpr int W = H + 2 * PAD;
  constexpr int ST1 = CIN + 4;
  constexpr int CINQ = CIN / 4;
  constexpr int CQ = CG / 4;                 // channel lanes
  constexpr int NT = CQ * 8 * REPS;
  constexpr int CLT = CLEN / REPS;           // k per thread
  constexpr int RROWS = (CLT * 8) / H;       // rows per replica

  __shared__ __align__(16) float sin_[RALLOC * W * ST1];

  int b = blockIdx.x;
  int leaf = b % NLEAF;
  int n = b / NLEAF;
  int t = threadIdx.x;
  int r0 = leaf * BROWS - PAD;

  for (int i = t; i < RALLOC * W * ST1; i += NT) sin_[i] = 0.f;
  __syncthreads();
  STAGE_COMP(Xr)
  __syncthreads();

  int rep = t / (CQ * 8);
  int tt = t % (CQ * 8);
  int c0l = tt >> 3, j = tt & 7;
  const float* jbp = sin_ + ((REPS > 1 ? rep * RROWS : 0) * W + j) * ST1;
  const float* wrb[4];
  const float* wib[4];
#pragma unroll
  for (int ch = 0; ch < 4; ++ch) {
    int c = coff + c0l + ch * CQ;
    wrb[ch] = wrT + (size_t)c * CIN * KK;
    wib[ch] = wiT + (size_t)c * CIN * KK;
  }

  float A[4][CLT], Bq[4][CLT], Cc[4][CLT], D[4][CLT];
#pragma unroll
  for (int ch = 0; ch < 4; ++ch)
#pragma unroll
    for (int k = 0; k < CLT; ++k) {
      A[ch][k] = 0.f; Bq[ch][k] = 0.f; Cc[ch][k] = 0.f; D[ch][k] = 0.f;
    }

#define STORE4_TAPS(PH)                                                       \
  for (int ky = 0; ky < K; ++ky) {                                            \
    for (int kx = 0; kx < K; ++kx) {                                          \
      const float* tb = jbp + (ky * W + kx) * ST1;                            \
      int woff = (ky * K + kx) * CIN;                                         \
      _Pragma("unroll 2") for (int cq = 0; cq < CINQ; ++cq) {                 \
        const float* tbc = tb + cq * 4;                                       \
        float4 wRv[4], wIv[4];                                                \
        _Pragma("unroll") for (int ch = 0; ch < 4; ++ch) {                    \
          wRv[ch] = *(const float4*)(wrb[ch] + woff + cq * 4);                \
          wIv[ch] = *(const float4*)(wib[ch] + woff + cq * 4);                \
        }                                                                     \
        _Pragma("unroll") for (int k = 0; k < CLT; ++k) {                     \
          float4 v4 = *(const float4*)(tbc +                                  \
              (((k * 8) / H) * W + ((k * 8) % H)) * ST1);                     \
          if (PH == 0) {                                                      \
            PFMA8(A[0][k], D[0][k], wRv[0], wIv[0])                           \
            PFMA8(A[1][k], D[1][k], wRv[1], wIv[1])                           \
            PFMA8(A[2][k], D[2][k], wRv[2], wIv[2])                           \
            PFMA8(A[3][k], D[3][k], wRv[3], wIv[3])                           \
          } else {                                                            \
            PFMA8(Bq[0][k], Cc[0][k], wIv[0], wRv[0])                         \
            PFMA8(Bq[1][k], Cc[1][k], wIv[1], wRv[1])                         \
            PFMA8(Bq[2][k], Cc[2][k], wIv[2], wRv[2])                         \
            PFMA8(Bq[3][k], Cc[3][k], wIv[3], wRv[3])                         \
          }                                                                   \
        }                                                                     \
      }                                                                       \
    }                                                                         \
  }

  STORE4_TAPS(0)
  __syncthreads();
  STAGE_COMP(Xi)
  __syncthreads();
  STORE4_TAPS(1)
#undef STORE4_TAPS

#pragma unroll
  for (int ch = 0; ch < 4; ++ch) {
    int c = coff + c0l + ch * CQ;
    float cbR = br[c], cbI = bi[c];
    size_t bbase = ((size_t)n * CG + (c0l + ch * CQ)) * HH;
#pragma unroll
    for (int k = 0; k < CLT; ++k) {
      int px = leaf * CLEN * 8 + (rep * CLT + k) * 8 + j;
      float yr = __fsub_rn(__fadd_rn(A[ch][k], cbR), __fadd_rn(Bq[ch][k], cbI));
      float yi = __fadd_rn(__fadd_rn(Cc[ch][k], cbR), __fadd_rn(D[ch][k], cbI));
      bufR[bbase + px] = yr;
      bufI[bbase + px] = yi;
    }
  }
}

// Stream stats: reads stored conv, sums in the EXACT chain order (leaf,j,k),
// same leaf-pair reduce, same partial layout (C=CG local channels).
template <int CG, int HH, int CLEN, int PASS>
__global__ __launch_bounds__(CG * 8) void cstats_stream(
    const float* __restrict__ bufR, const float* __restrict__ bufI,
    const float* __restrict__ coef, float* __restrict__ partial, int coff) {
  constexpr int NLEAF = HH / (8 * CLEN);
  constexpr int NT = CG * 8;
  __shared__ float red0[NT], red1[NT], red2[PASS ? NT : 1];
  int b = blockIdx.x;
  int leaf = b % NLEAF;
  int n = b / NLEAF;
  int t = threadIdx.x;
  int cl = t >> 3, j = t & 7;
  int c = coff + cl;
  size_t base = ((size_t)n * CG + cl) * HH + leaf * CLEN * 8 + j;
  float mr = 0.f, mi = 0.f;
  if (PASS) { mr = coef[c * 5 + 0]; mi = coef[c * 5 + 1]; }
  float a0 = 0.f, a1 = 0.f, a2 = 0.f;
#pragma unroll
  for (int k = 0; k < CLEN; ++k) {
    float yr = bufR[base + k * 8];
    float yi = bufI[base + k * 8];
    if (PASS == 0) {
      a0 = __fadd_rn(a0, yr);
      a1 = __fadd_rn(a1, yi);
    } else {
      float cr = __fsub_rn(yr, mr), ci = __fsub_rn(yi, mi);
      a0 = __fadd_rn(a0, __fmul_rn(cr, cr));
      a1 = __fadd_rn(a1, __fmul_rn(ci, ci));
      a2 = __fadd_rn(a2, __fmul_rn(cr, ci));
    }
  }
  red0[t] = a0; red1[t] = a1; if (PASS) red2[t] = a2;
  __syncthreads();
  if (j == 0) {
    constexpr int S = PASS ? 3 : 2;
    int o = cl * 8;
    size_t pb = (((size_t)n * CG + cl) * NLEAF + leaf) * S;
    partial[pb + 0] =
        __fadd_rn(__fadd_rn(__fadd_rn(red0[o], red0[o + 1]), __fadd_rn(red0[o + 2], red0[o + 3])),
                  __fadd_rn(__fadd_rn(red0[o + 4], red0[o + 5]), __fadd_rn(red0[o + 6], red0[o + 7])));
    partial[pb + 1] =
        __fadd_rn(__fadd_rn(__fadd_rn(red1[o], red1[o + 1]), __fadd_rn(red1[o + 2], red1[o + 3])),
                  __fadd_rn(__fadd_rn(red1[o + 4], red1[o + 5]), __fadd_rn(red1[o + 6], red1[o + 7])));
    if (PASS)
      partial[pb + 2] =
          __fadd_rn(__fadd_rn(__fadd_rn(red2[o], red2[o + 1]), __fadd_rn(red2[o + 2], red2[o + 3])),
                    __fadd_rn(__fadd_rn(red2[o + 4], red2[o + 5]), __fadd_rn(red2[o + 6], red2[o + 7])));
  }
}

// Stream pool: reads stored conv, BN+argmax in the exact candidate order.
template <int CG, int H, int COUT>
__global__ __launch_bounds__(256) void cpool_stream(
    const float* __restrict__ bufR, const float* __restrict__ bufI,
    const float* __restrict__ coef, const float* __restrict__ grr,
    const float* __restrict__ gri, const float* __restrict__ gii,
    const float* __restrict__ bbr, const float* __restrict__ bbi,
    float* __restrict__ Pr, float* __restrict__ Pi, int coff) {
  constexpr int OH = H / 2, OHH = OH * OH, HH = H * H;
  int n = blockIdx.x;
  for (int idx = threadIdx.x; idx < CG * OHH; idx += 256) {
    int cl = idx / OHH, q = idx % OHH;
    int oy = q / OH, ox = q % OH;
    int c = coff + cl;
    size_t base = ((size_t)n * CG + cl) * HH;
    const float* cf = coef + c * 5;
    float gR = grr[c], gI = gri[c], gG = gii[c], bR = bbr[c], bI2 = bbi[c];
    float bestr = 0.f, besti = 0.f, bestm = -1.f;
#pragma unroll
    for (int p = 0; p < 4; ++p) {
      size_t o = base + (size_t)(2 * oy + (p >> 1)) * H + 2 * ox + (p & 1);
      float xr = bufR[o], xi = bufI[o];
      float yr, yi;
      bn_apply_f32(xr, xi, cf, gR, gI, gG, bR, bI2, yr, yi);
      float m = __fadd_rn(__fmul_rn(yr, yr), __fmul_rn(yi, yi));
      if (m > bestm) { bestm = m; bestr = yr; besti = yi; }
    }
    size_t o = ((size_t)(n * COUT + c) * OH + oy) * OH + ox;
    Pr[o] = bestr;
    Pi[o] = besti;
  }
}

// ---- combine over n (sequential fp32, numpy outer-axis order), then coef.
// NLEAF=32 reproduces conv1's in-block 32-leaf adjacent-pair tree verbatim.
template <int C, int NLEAF, int TPB>
__global__ __launch_bounds__(TPB) void np_mean_combine3(
    const float* __restrict__ partial, float* __restrict__ coef, float Mf,
    int coff) {
  int t = threadIdx.x;
  if (t >= C * 2) return;
  int c = t >> 1, s = t & 1;
  float acc = 0.f;
  for (int n = 0; n < 512; ++n) {
    const float* p = partial + (((size_t)n * C + c) * NLEAF) * 2 + s;
    float v;
    if (NLEAF == 32) {
      float q[32];
#pragma unroll
      for (int i = 0; i < 32; ++i) q[i] = p[i * 2];
#pragma unroll
      for (int wd = 32; wd > 1; wd >>= 1)
#pragma unroll
        for (int i = 0; i < (wd >> 1); ++i) q[i] = __fadd_rn(q[2 * i], q[2 * i + 1]);
      v = q[0];
    } else if (NLEAF == 8)
      v = __fadd_rn(__fadd_rn(__fadd_rn(p[0], p[2]), __fadd_rn(p[4], p[6])),
                    __fadd_rn(__fadd_rn(p[8], p[10]), __fadd_rn(p[12], p[14])));
    else if (NLEAF == 2)
      v = __fadd_rn(p[0], p[2]);
    else
      v = p[0];
    acc = __fadd_rn(acc, v);
  }
  coef[(coff + c) * 5 + s] = __fdiv_rn(acc, Mf);
}

template <int C, int NLEAF, int TPB>
__global__ __launch_bounds__(TPB) void np_cov_combine3(
    const float* __restrict__ partial, float* __restrict__ coef, float Mf,
    int coff) {
  __shared__ float sums[C * 3];
  int t = threadIdx.x;
  if (t < C * 3) {
    int c = t / 3, s = t % 3;
    float acc = 0.f;
    for (int n = 0; n < 512; ++n) {
      const float* p = partial + (((size_t)n * C + c) * NLEAF) * 3 + s;
      float v;
      if (NLEAF == 32) {
        float q[32];
#pragma unroll
        for (int i = 0; i < 32; ++i) q[i] = p[i * 3];
#pragma unroll
        for (int wd = 32; wd > 1; wd >>= 1)
#pragma unroll
          for (int i = 0; i < (wd >> 1); ++i) q[i] = __fadd_rn(q[2 * i], q[2 * i + 1]);
        v = q[0];
      } else if (NLEAF == 8)
        v = __fadd_rn(__fadd_rn(__fadd_rn(p[0], p[3]), __fadd_rn(p[6], p[9])),
                      __fadd_rn(__fadd_rn(p[12], p[15]), __fadd_rn(p[18], p[21])));
      else if (NLEAF == 2)
        v = __fadd_rn(p[0], p[3]);
      else
        v = p[0];
      acc = __fadd_rn(acc, v);
    }
    sums[c * 3 + s] = acc;
  }
  __syncthreads();
  if (t < C) {
    float Crr = __fadd_rn(__fdiv_rn(sums[t * 3 + 0], Mf), 1e-5f);
    float Cii = __fadd_rn(__fdiv_rn(sums[t * 3 + 1], Mf), 1e-5f);
    float Cri = __fdiv_rn(sums[t * 3 + 2], Mf);
    float s_ = __fsqrt_rn(__fsub_rn(__fmul_rn(Crr, Cii), __fmul_rn(Cri, Cri)));
    float t_ = __fsqrt_rn(__fadd_rn(__fadd_rn(Crr, Cii), __fmul_rn(2.f, s_)));
    float inv = __fdiv_rn(1.f, __fmul_rn(s_, t_));
    int cg = coff + t;
    coef[cg * 5 + 2] = __fmul_rn(__fadd_rn(Cii, s_), inv);   // Rrr
    coef[cg * 5 + 3] = __fmul_rn(__fadd_rn(Crr, s_), inv);   // Rii
    coef[cg * 5 + 4] = __fmul_rn(-Cri, inv);                 // Rri
  }
}

// ---------------- fused FC head (fp64 accumulate; transposed weights)
__global__ __launch_bounds__(256) void fc_head_kernel(
    const float* __restrict__ Fr, const float* __restrict__ Fi,
    const float* __restrict__ wrT, const float* __restrict__ wiT,
    const float* __restrict__ br, const float* __restrict__ bi,
    const float* __restrict__ w2T, const float* __restrict__ b2,
    float* __restrict__ logits, float* __restrict__ er_out,
    float* __restrict__ ei_out) {
  int n = blockIdx.x, t = threadIdx.x;
  __shared__ float sFr[1024], sFi[1024];
  __shared__ double sMag[256];
  for (int idx = t; idx < 1024; idx += 256) {
    sFr[idx] = Fr[(size_t)n * 1024 + idx];
    sFi[idx] = Fi[(size_t)n * 1024 + idx];
  }
  __syncthreads();
  {
    double er = 0.0, ei = 0.0;
    for (int k = 0; k < 1024; ++k) {
      double fx = (double)sFr[k], fy = (double)sFi[k];
      double a = (double)wrT[(size_t)k * 256 + t];
      double bb = (double)wiT[(size_t)k * 256 + t];
      er += fx * a - fy * bb;
      ei += fy * a + fx * bb;
    }
    double bR = (double)br[t], bI = (double)bi[t];
    er = fmax(er + (bR - bI), 0.0);
    ei = fmax(ei + (bR + bI), 0.0);
    er_out[(size_t)n * 256 + t] = (float)er;
    ei_out[(size_t)n * 256 + t] = (float)ei;
    sMag[t] = sqrt(er * er + ei * ei + 1e-12);
  }
  __syncthreads();
#pragma unroll
  for (int j = 0; j < 4; ++j) {
    int o = j * 256 + t;
    if (o < 1000) {
      double acc = 0.0;
      for (int k = 0; k < 256; ++k)
        acc += sMag[k] * (double)w2T[(size_t)k * 1000 + o];
      logits[(size_t)n * 1000 + o] = (float)(acc + (double)b2[o]);
    }
  }
}

// ---------------- launch
extern "C" void kernel_launch(void* const* d_in, const int* in_sizes, int n_in,
                              void* d_out, int out_size, void* d_ws,
                              size_t ws_size, hipStream_t stream) {
  (void)in_sizes; (void)n_in;
  const float* x = (const float*)d_in[0];
  const float* c1_wr = (const float*)d_in[1];
  const float* c1_wi = (const float*)d_in[2];
  const float* c1_br = (const float*)d_in[3];
  const float* c1_bi = (const float*)d_in[4];
  const float* c2_wr = (const float*)d_in[5];
  const float* c2_wi = (const float*)d_in[6];
  const float* c2_br = (const float*)d_in[7];
  const float* c2_bi = (const float*)d_in[8];
  const float* c3_wr = (const float*)d_in[9];
  const float* c3_wi = (const float*)d_in[10];
  const float* c3_br = (const float*)d_in[11];
  const float* c3_bi = (const float*)d_in[12];
  const float* c4_wr = (const float*)d_in[13];
  const float* c4_wi = (const float*)d_in[14];
  const float* c4_br = (const float*)d_in[15];
  const float* c4_bi = (const float*)d_in[16];
  const float* b1_grr = (const float*)d_in[17];
  const float* b1_gri = (const float*)d_in[18];
  const float* b1_gii = (const float*)d_in[19];
  const float* b1_br = (const float*)d_in[20];
  const float* b1_bi = (const float*)d_in[21];
  const float* b2_grr = (const float*)d_in[22];
  const float* b2_gri = (const float*)d_in[23];
  const float* b2_gii = (const float*)d_in[24];
  const float* b2_br = (const float*)d_in[25];
  const float* b2_bi = (const float*)d_in[26];
  const float* b3_grr = (const float*)d_in[27];
  const float* b3_gri = (const float*)d_in[28];
  const float* b3_gii = (const float*)d_in[29];
  const float* b3_br = (const float*)d_in[30];
  const float* b3_bi = (const float*)d_in[31];
  const float* b4_grr = (const float*)d_in[32];
  const float* b4_gri = (const float*)d_in[33];
  const float* b4_gii = (const float*)d_in[34];
  const float* b4_br = (const float*)d_in[35];
  const float* b4_bi = (const float*)d_in[36];
  const float* fc1_wr = (const float*)d_in[37];
  const float* fc1_wi = (const float*)d_in[38];
  const float* fc1_br = (const float*)d_in[39];
  const float* fc1_bi = (const float*)d_in[40];
  const float* fc2_w = (const float*)d_in[41];
  const float* fc2_b = (const float*)d_in[42];

  float* outL = (float*)d_out;
  float* er = outL + 512 * 1000;
  float* ei = er + 512 * 256;

  // Workspace tiers:
  //   NEED  (101,057,792): base layout (proven).
  //   NEED2 (135,005,440): +L2 store-once CG=8.
  //   NEED3 (236,848,384): +L2 store-once CG=32; also enables conv1
  //         store-once (buf1 reuses buf2R3/buf2I3 slots, dead before L2;
  //         partial1 @67,108,864 = P2 region, dead during all of L1).
  const size_t NEED = 101057792;
  const size_t NEED2 = 135005440;
  const size_t NEED3 = 236848384;
  if (ws_size < NEED) {
    fill_kernel<<<(out_size + 255) / 256, 256, 0, stream>>>(
        (float*)d_out, out_size, (float)(ws_size >> 20));
    return;
  }
  const bool big3 = (ws_size >= NEED3);
  const bool big = (ws_size >= NEED2);
  char* w = (char*)d_ws;
  float* P1r = (float*)(w + 0);
  float* P1i = (float*)(w + 33554432);
  float* P2r = (float*)(w + 67108864);
  float* P2i = (float*)(w + 83886080);
  float* P3r = (float*)(w + 0);
  float* P3i = (float*)(w + 8388608);
  float* P4r = (float*)(w + 16777216);
  float* P4i = (float*)(w + 18874368);
  float* partialT = (float*)(w + 100663296);
  float* partial2 = (float*)(w + 67108864);   // fallback L2 leaf partials
  float* coef = (float*)(w + 101056512);
  float* c2_wrT = (float*)(w + 100663296);
  float* c2_wiT = (float*)(w + 100663296 + 51200);
  float* c3_wrT = (float*)(w + 100663296);
  float* c3_wiT = (float*)(w + 100663296 + 73728);
  float* c4_wrT = (float*)(w + 20971520);
  float* c4_wiT = (float*)(w + 20971520 + 147456);
  float* fc1_wrT = (float*)(w + 33554432);
  float* fc1_wiT = (float*)(w + 34603008);
  float* fc2_wT = (float*)(w + 35651584);
  float* buf3R = (float*)(w + 16777216);
  float* buf3I = (float*)(w + 33554432);
  float* partial3s = (float*)(w + 50331648);
  float* buf4R = (float*)(w + 67108864);
  float* buf4I = (float*)(w + 75497472);
  // NEED2 tier (CG=8): buf2 @101,057,792 / @117,835,008; partial @134,612,224
  float* buf2R = (float*)(w + 101057792);
  float* buf2I = (float*)(w + 117835008);
  float* partial2g = (float*)(w + 134612224);
  // NEED3 tier (CG=32): buf2 @101,057,792 (67M) / @168,166,656 (67M);
  //   partial @235,275,520 (1,572,864)
  float* buf2R3 = (float*)(w + 101057792);
  float* buf2I3 = (float*)(w + 168166656);
  float* partial2g3 = (float*)(w + 235275520);
  // conv1 store-once (big3): buf1 64MB each in the (later) buf2R3/buf2I3
  //   slots — dead before L2. partial1 @67,108,864 (P2 region): P2 is first
  //   written by the L2 pool, strictly after all conv1 combines consumed
  //   partial1; does NOT overlap P1 @[0, 67,108,864).
  float* buf1R = (float*)(w + 101057792);
  float* buf1I = (float*)(w + 168166656);
  float* partial1 = (float*)(w + 67108864);

  // ---- layer 1 (C=16, M=2097152)
  if (big3) {
    // store-once: 2 channel-groups of 8
    for (int g = 0; g < 2; ++g) {
      conv1_store<<<1024, 256, 0, stream>>>(x, c1_wr, c1_wi, c1_br, c1_bi,
                                            g * 2, buf1R, buf1I);
      cstats_stream<8, 4096, 16, 0><<<16384, 64, 0, stream>>>(
          buf1R, buf1I, coef, partial1, g * 8);
      np_mean_combine3<8, 32, 64><<<1, 64, 0, stream>>>(partial1, coef,
                                                        2097152.f, g * 8);
      cstats_stream<8, 4096, 16, 1><<<16384, 64, 0, stream>>>(
          buf1R, buf1I, coef, partial1, g * 8);
      np_cov_combine3<8, 32, 64><<<1, 64, 0, stream>>>(partial1, coef,
                                                       2097152.f, g * 8);
      cpool_stream<8, 64, 16><<<512, 256, 0, stream>>>(
          buf1R, buf1I, coef, b1_grr, b1_gri, b1_gii, b1_br, b1_bi, P1r, P1i,
          g * 8);
    }
  } else {
    conv1_stats2<0><<<2048, 256, 0, stream>>>(x, c1_wr, c1_wi, c1_br, c1_bi,
                                              coef, partialT);
    np_mean_combine3<16, 1, 64><<<1, 64, 0, stream>>>(partialT, coef,
                                                      2097152.f, 0);
    conv1_stats2<1><<<2048, 256, 0, stream>>>(x, c1_wr, c1_wi, c1_br, c1_bi,
                                              coef, partialT);
    np_cov_combine3<16, 1, 64><<<1, 64, 0, stream>>>(partialT, coef,
                                                     2097152.f, 0);
    conv1_pool2<<<2048, 256, 0, stream>>>(x, c1_wr, c1_wi, c1_br, c1_bi, coef,
                                          b1_grr, b1_gri, b1_gii, b1_br,
                                          b1_bi, P1r, P1i);
  }

  // ---- layer 2 (H=32, CIN=16, COUT=32, K=5, M=524288)
  repack_w<<<50, 256, 0, stream>>>(c2_wr, c2_wrT, 16, 25, 12800);
  repack_w<<<50, 256, 0, stream>>>(c2_wi, c2_wiT, 16, 25, 12800);
  if (big3) {
    cconv_band_store<32, 16, 32, 32, 5, 2><<<4096, 256, 0, stream>>>(
        P1r, P1i, c2_wrT, c2_wiT, c2_br, c2_bi, 0, buf2R3, buf2I3);
    cstats_stream<32, 1024, 16, 0><<<4096, 256, 0, stream>>>(
        buf2R3, buf2I3, coef, partial2g3, 0);
    np_mean_combine3<32, 8, 64><<<1, 64, 0, stream>>>(partial2g3, coef,
                                                      524288.f, 0);
    cstats_stream<32, 1024, 16, 1><<<4096, 256, 0, stream>>>(
        buf2R3, buf2I3, coef, partial2g3, 0);
    np_cov_combine3<32, 8, 128><<<1, 128, 0, stream>>>(partial2g3, coef,
                                                       524288.f, 0);
    cpool_stream<32, 32, 32><<<512, 256, 0, stream>>>(
        buf2R3, buf2I3, coef, b2_grr, b2_gri, b2_gii, b2_br, b2_bi, P2r, P2i,
        0);
  } else if (big) {
    for (int g = 0; g < 4; ++g) {
      cconv_band_store<32, 16, 32, 8, 5, 4><<<4096, 128, 0, stream>>>(
          P1r, P1i, c2_wrT, c2_wiT, c2_br, c2_bi, g * 8, buf2R, buf2I);
      cstats_stream<8, 1024, 16, 0><<<4096, 64, 0, stream>>>(
          buf2R, buf2I, coef, partial2g, g * 8);
      np_mean_combine3<8, 8, 64><<<1, 64, 0, stream>>>(partial2g, coef,
                                                       524288.f, g * 8);
      cstats_stream<8, 1024, 16, 1><<<4096, 64, 0, stream>>>(
          buf2R, buf2I, coef, partial2g, g * 8);
      np_cov_combine3<8, 8, 64><<<1, 64, 0, stream>>>(partial2g, coef,
                                                      524288.f, g * 8);
      cpool_stream<8, 32, 32><<<512, 256, 0, stream>>>(
          buf2R, buf2I, coef, b2_grr, b2_gri, b2_gii, b2_br, b2_bi, P2r, P2i,
          g * 8);
    }
  } else {
    cconv_band_stats<32, 16, 32, 5, 0><<<4096, 128, 0, stream>>>(
        P1r, P1i, c2_wrT, c2_wiT, c2_br, c2_bi, coef, partial2);
    np_mean_combine3<32, 8, 64><<<1, 64, 0, stream>>>(partial2, coef,
                                                      524288.f, 0);
    cconv_band_stats<32, 16, 32, 5, 1><<<4096, 128, 0, stream>>>(
        P1r, P1i, c2_wrT, c2_wiT, c2_br, c2_bi, coef, partial2);
    np_cov_combine3<32, 8, 128><<<1, 128, 0, stream>>>(partial2, coef,
                                                       524288.f, 0);
    cconv_band_pool<32, 16, 32, 5, 2><<<4096, 128, 0, stream>>>(
        P1r, P1i, c2_wrT, c2_wiT, c2_br, c2_bi, coef, b2_grr, b2_gri, b2_gii,
        b2_br, b2_bi, P2r, P2i);
  }

  // ---- layer 3 (H=16, CIN=32, COUT=64, K=3, M=131072) — store-once, G=2,
  //      4-channel/thread store (256 threads, REPS=4)
  repack_w<<<72, 256, 0, stream>>>(c3_wr, c3_wrT, 32, 9, 18432);
  repack_w<<<72, 256, 0, stream>>>(c3_wi, c3_wiT, 32, 9, 18432);
  for (int g = 0; g < 2; ++g) {
    cconv_band_store4<16, 32, 64, 32, 3, 4><<<1024, 256, 0, stream>>>(
        P2r, P2i, c3_wrT, c3_wiT, c3_br, c3_bi, g * 32, buf3R, buf3I);
    cstats_stream<32, 256, 16, 0><<<1024, 256, 0, stream>>>(
        buf3R, buf3I, coef, partial3s, g * 32);
    np_mean_combine3<32, 2, 64><<<1, 64, 0, stream>>>(partial3s, coef,
                                                      131072.f, g * 32);
    cstats_stream<32, 256, 16, 1><<<1024, 256, 0, stream>>>(
        buf3R, buf3I, coef, partial3s, g * 32);
    np_cov_combine3<32, 2, 128><<<1, 128, 0, stream>>>(partial3s, coef,
                                                       131072.f, g * 32);
    cpool_stream<32, 16, 64><<<512, 256, 0, stream>>>(
        buf3R, buf3I, coef, b3_grr, b3_gri, b3_gii, b3_br, b3_bi, P3r, P3i,
        g * 32);
  }

  // ---- layer 4 (H=8, CIN=64, COUT=64, K=3, M=32768) — store-once, G=1,
  //      4-channel/thread store (256 threads, REPS=2)
  repack_w<<<144, 256, 0, stream>>>(c4_wr, c4_wrT, 64, 9, 36864);
  repack_w<<<144, 256, 0, stream>>>(c4_wi, c4_wiT, 64, 9, 36864);
  cconv_band_store4<8, 64, 64, 64, 3, 2><<<512, 256, 0, stream>>>(
      P3r, P3i, c4_wrT, c4_wiT, c4_br, c4_bi, 0, buf4R, buf4I);
  cstats_stream<64, 64, 8, 0><<<512, 512, 0, stream>>>(buf4R, buf4I, coef,
                                                       partialT, 0);
  np_mean_combine3<64, 1, 128><<<1, 128, 0, stream>>>(partialT, coef,
                                                      32768.f, 0);
  cstats_stream<64, 64, 8, 1><<<512, 512, 0, stream>>>(buf4R, buf4I, coef,
                                                       partialT, 0);
  np_cov_combine3<64, 1, 192><<<1, 192, 0, stream>>>(partialT, coef,
                                                     32768.f, 0);
  cpool_stream<64, 8, 64><<<512, 256, 0, stream>>>(
      buf4R, buf4I, coef, b4_grr, b4_gri, b4_gii, b4_br, b4_bi, P4r, P4i, 0);

  // ---- FC head (weights transposed into dead P1i region)
  transpose_rc<<<1024, 256, 0, stream>>>(fc1_wr, fc1_wrT, 256, 1024);
  transpose_rc<<<1024, 256, 0, stream>>>(fc1_wi, fc1_wiT, 256, 1024);
  transpose_rc<<<1000, 256, 0, stream>>>(fc2_w, fc2_wT, 1000, 256);
  fc_head_kernel<<<512, 256, 0, stream>>>(P4r, P4i, fc1_wrT, fc1_wiT, fc1_br,
                                          fc1_bi, fc2_wT, fc2_b, outL, er, ei);
}

// Round 14
// 2481.872 us; speedup vs baseline: 1.2175x; 1.2175x over previous
//
#include <hip/hip_runtime.h>
#include <math.h>

__global__ __launch_bounds__(256) void fill_kernel(float* p, int n, float v) {
  int i = blockIdx.x * 256 + threadIdx.x;
  if (i < n) p[i] = v;
}

// ---------------- strict-fp32 BN apply (reference op order, unfolded)
// coef[c*5]: mr, mi, Rrr, Rii, Rri
__device__ __forceinline__ void bn_apply_f32(float xr, float xi,
                                             const float* __restrict__ cf,
                                             float grr, float gri, float gii,
                                             float bbr, float bbi, float& yr,
                                             float& yi) {
  float cr = __fsub_rn(xr, cf[0]);
  float ci = __fsub_rn(xi, cf[1]);
  float xhr = __fadd_rn(__fmul_rn(cf[2], cr), __fmul_rn(cf[4], ci));
  float xhi = __fadd_rn(__fmul_rn(cf[4], cr), __fmul_rn(cf[3], ci));
  yr = fmaxf(__fadd_rn(__fadd_rn(__fmul_rn(grr, xhr), __fmul_rn(gri, xhi)), bbr), 0.f);
  yi = fmaxf(__fadd_rn(__fadd_rn(__fmul_rn(gri, xhr), __fmul_rn(gii, xhi)), bbi), 0.f);
}

// 8 FMAs: two chains fed by one float4 read (v4), cin order ascending.
#define PFMA8(XX, YY, WV1, WV2) \
  XX = fmaf(v4.x, WV1.x, XX);   \
  XX = fmaf(v4.y, WV1.y, XX);   \
  XX = fmaf(v4.z, WV1.z, XX);   \
  XX = fmaf(v4.w, WV1.w, XX);   \
  YY = fmaf(v4.x, WV2.x, YY);   \
  YY = fmaf(v4.y, WV2.y, YY);   \
  YY = fmaf(v4.z, WV2.z, YY);   \
  YY = fmaf(v4.w, WV2.w, YY);

// ================= conv1 (cin=1, K=11) ====================================
#define C1_ROWBASE(pr) ((pr) * 84 + (((pr) >> 1) & 1))

template <int PASS>
__global__ __launch_bounds__(256, 2) void conv1_stats2(
    const float* __restrict__ x, const float* __restrict__ wr,
    const float* __restrict__ wi, const float* __restrict__ br,
    const float* __restrict__ bi, const float* __restrict__ coef,
    float* __restrict__ partial) {
  int b = blockIdx.x;
  int n = b >> 2, cg = b & 3;  // 4 channels per block
  int t = threadIdx.x;
  __shared__ __align__(16) float sx[74 * 84];
  __shared__ __align__(16) float4 swr4[121], swi4[121];  // [tap][ci]
  __shared__ float s0[256], s1[256], s2[PASS ? 256 : 1];

  for (int i = t; i < 74 * 84; i += 256) sx[i] = 0.f;
  for (int idx = t; idx < 484; idx += 256) {
    int wo = idx >> 2, ci = idx & 3;
    ((float*)swr4)[idx] = wr[(size_t)(cg * 4 + ci) * 121 + wo];
    ((float*)swi4)[idx] = wi[(size_t)(cg * 4 + ci) * 121 + wo];
  }
  __syncthreads();
  const float* xn = x + (size_t)n * 4096;
  for (int idx = t; idx < 1024; idx += 256) {
    float4 v = *(const float4*)(xn + idx * 4);
    int iy = idx >> 4, ixb = (idx & 15) * 4;
    int base = C1_ROWBASE(iy + 5) + ixb + 5;
    sx[base + 0] = v.x; sx[base + 1] = v.y;
    sx[base + 2] = v.z; sx[base + 3] = v.w;
  }
  __syncthreads();

  int leaf = t >> 3, j = t & 7;
  float a[4][16], bb[4][16];
#pragma unroll
  for (int ci = 0; ci < 4; ++ci)
#pragma unroll
    for (int k = 0; k < 16; ++k) { a[ci][k] = 0.f; bb[ci][k] = 0.f; }

  for (int ky = 0; ky < 11; ++ky) {
    int pr0 = leaf * 2 + ky;
    int base0 = C1_ROWBASE(pr0) + j;
    int base1 = C1_ROWBASE(pr0 + 1) + j;
    for (int kx = 0; kx < 11; ++kx) {
      const float* tb0 = sx + base0 + kx;
      const float* tb1 = sx + base1 + kx;
      float4 wR = swr4[ky * 11 + kx];
      float4 wI = swi4[ky * 11 + kx];
#pragma unroll
      for (int k8 = 0; k8 < 8; ++k8) {
        float v = tb0[k8 * 8];
        a[0][k8] = fmaf(v, wR.x, a[0][k8]);  bb[0][k8] = fmaf(v, wI.x, bb[0][k8]);
        a[1][k8] = fmaf(v, wR.y, a[1][k8]);  bb[1][k8] = fmaf(v, wI.y, bb[1][k8]);
        a[2][k8] = fmaf(v, wR.z, a[2][k8]);  bb[2][k8] = fmaf(v, wI.z, bb[2][k8]);
        a[3][k8] = fmaf(v, wR.w, a[3][k8]);  bb[3][k8] = fmaf(v, wI.w, bb[3][k8]);
      }
#pragma unroll
      for (int k8 = 0; k8 < 8; ++k8) {
        float v = tb1[k8 * 8];
        a[0][8 + k8] = fmaf(v, wR.x, a[0][8 + k8]);  bb[0][8 + k8] = fmaf(v, wI.x, bb[0][8 + k8]);
        a[1][8 + k8] = fmaf(v, wR.y, a[1][8 + k8]);  bb[1][8 + k8] = fmaf(v, wI.y, bb[1][8 + k8]);
        a[2][8 + k8] = fmaf(v, wR.z, a[2][8 + k8]);  bb[2][8 + k8] = fmaf(v, wI.z, bb[2][8 + k8]);
        a[3][8 + k8] = fmaf(v, wR.w, a[3][8 + k8]);  bb[3][8 + k8] = fmaf(v, wI.w, bb[3][8 + k8]);
      }
    }
  }

#pragma unroll
  for (int ci = 0; ci < 4; ++ci) {
    int c = cg * 4 + ci;
    float addR = __fsub_rn(br[c], bi[c]);
    float addI = __fadd_rn(br[c], bi[c]);
    float mr = 0.f, mi = 0.f;
    if (PASS) { mr = coef[c * 5 + 0]; mi = coef[c * 5 + 1]; }
    float a0 = 0.f, a1 = 0.f, a2 = 0.f;
#pragma unroll
    for (int k = 0; k < 16; ++k) {
      float xr = __fadd_rn(a[ci][k], addR);
      float xi = __fadd_rn(bb[ci][k], addI);
      if (PASS == 0) {
        a0 = __fadd_rn(a0, xr);
        a1 = __fadd_rn(a1, xi);
      } else {
        float cr = __fsub_rn(xr, mr), ci2 = __fsub_rn(xi, mi);
        a0 = __fadd_rn(a0, __fmul_rn(cr, cr));
        a1 = __fadd_rn(a1, __fmul_rn(ci2, ci2));
        a2 = __fadd_rn(a2, __fmul_rn(cr, ci2));
      }
    }
    s0[t] = a0; s1[t] = a1; if (PASS) s2[t] = a2;
    __syncthreads();
    if (t < 32) {
      int o = t * 8;
      float v0 = __fadd_rn(__fadd_rn(__fadd_rn(s0[o], s0[o + 1]), __fadd_rn(s0[o + 2], s0[o + 3])),
                           __fadd_rn(__fadd_rn(s0[o + 4], s0[o + 5]), __fadd_rn(s0[o + 6], s0[o + 7])));
      float v1 = __fadd_rn(__fadd_rn(__fadd_rn(s1[o], s1[o + 1]), __fadd_rn(s1[o + 2], s1[o + 3])),
                           __fadd_rn(__fadd_rn(s1[o + 4], s1[o + 5]), __fadd_rn(s1[o + 6], s1[o + 7])));
      float v2 = 0.f;
      if (PASS)
        v2 = __fadd_rn(__fadd_rn(__fadd_rn(s2[o], s2[o + 1]), __fadd_rn(s2[o + 2], s2[o + 3])),
                       __fadd_rn(__fadd_rn(s2[o + 4], s2[o + 5]), __fadd_rn(s2[o + 6], s2[o + 7])));
      s0[t] = v0; s1[t] = v1; if (PASS) s2[t] = v2;
    }
    if (t == 0) {
      for (int wdt = 32; wdt > 1; wdt >>= 1)
        for (int i = 0; i < (wdt >> 1); ++i) {
          s0[i] = __fadd_rn(s0[2 * i], s0[2 * i + 1]);
          s1[i] = __fadd_rn(s1[2 * i], s1[2 * i + 1]);
          if (PASS) s2[i] = __fadd_rn(s2[2 * i], s2[2 * i + 1]);
        }
      constexpr int S = PASS ? 3 : 2;
      size_t base = ((size_t)(n * 16 + c)) * S;
      partial[base + 0] = s0[0];
      partial[base + 1] = s1[0];
      if (PASS) partial[base + 2] = s2[0];
    }
    __syncthreads();
  }
}

__global__ __launch_bounds__(256, 2) void conv1_pool2(
    const float* __restrict__ x, const float* __restrict__ wr,
    const float* __restrict__ wi, const float* __restrict__ br,
    const float* __restrict__ bi, const float* __restrict__ coef,
    const float* __restrict__ grr, const float* __restrict__ gri,
    const float* __restrict__ gii, const float* __restrict__ bbr,
    const float* __restrict__ bbi, float* __restrict__ Pr,
    float* __restrict__ Pi) {
  int b = blockIdx.x;
  int n = b >> 2, cg = b & 3;
  int t = threadIdx.x;
  __shared__ __align__(16) float sx[74 * 84];
  __shared__ __align__(16) float4 swr4[121], swi4[121];

  for (int i = t; i < 74 * 84; i += 256) sx[i] = 0.f;
  for (int idx = t; idx < 484; idx += 256) {
    int wo = idx >> 2, ci = idx & 3;
    ((float*)swr4)[idx] = wr[(size_t)(cg * 4 + ci) * 121 + wo];
    ((float*)swi4)[idx] = wi[(size_t)(cg * 4 + ci) * 121 + wo];
  }
  __syncthreads();
  const float* xn = x + (size_t)n * 4096;
  for (int idx = t; idx < 1024; idx += 256) {
    float4 v = *(const float4*)(xn + idx * 4);
    int iy = idx >> 4, ixb = (idx & 15) * 4;
    int base = C1_ROWBASE(iy + 5) + ixb + 5;
    sx[base + 0] = v.x; sx[base + 1] = v.y;
    sx[base + 2] = v.z; sx[base + 3] = v.w;
  }
  __syncthreads();

  int oyb = t >> 5, ox = t & 31;
  float A[4][16], Bb[4][16];
#pragma unroll
  for (int ci = 0; ci < 4; ++ci)
#pragma unroll
    for (int e = 0; e < 16; ++e) { A[ci][e] = 0.f; Bb[ci][e] = 0.f; }

  for (int ky = 0; ky < 11; ++ky) {
    for (int kx = 0; kx < 11; ++kx) {
      float4 wR = swr4[ky * 11 + kx];
      float4 wI = swi4[ky * 11 + kx];
#pragma unroll
      for (int e = 0; e < 16; ++e) {
        int i = e >> 2, p = e & 3;
        int pr = 2 * (oyb + i * 8) + (p >> 1) + ky;
        int pc = 2 * ox + (p & 1) + kx;
        float v = sx[C1_ROWBASE(pr) + pc];
        A[0][e] = fmaf(v, wR.x, A[0][e]);  Bb[0][e] = fmaf(v, wI.x, Bb[0][e]);
        A[1][e] = fmaf(v, wR.y, A[1][e]);  Bb[1][e] = fmaf(v, wI.y, Bb[1][e]);
        A[2][e] = fmaf(v, wR.z, A[2][e]);  Bb[2][e] = fmaf(v, wI.z, Bb[2][e]);
        A[3][e] = fmaf(v, wR.w, A[3][e]);  Bb[3][e] = fmaf(v, wI.w, Bb[3][e]);
      }
    }
  }

#pragma unroll
  for (int ci = 0; ci < 4; ++ci) {
    int c = cg * 4 + ci;
    float addR = __fsub_rn(br[c], bi[c]);
    float addI = __fadd_rn(br[c], bi[c]);
    const float* cf = coef + c * 5;
    float gR = grr[c], gI = gri[c], gG = gii[c], bR = bbr[c], bI2 = bbi[c];
#pragma unroll
    for (int i = 0; i < 4; ++i) {
      int oy = oyb + i * 8;
      float bestr = 0.f, besti = 0.f, bestm = -1.f;
#pragma unroll
      for (int p = 0; p < 4; ++p) {
        float xr = __fadd_rn(A[ci][i * 4 + p], addR);
        float xi = __fadd_rn(Bb[ci][i * 4 + p], addI);
        float yr, yi;
        bn_apply_f32(xr, xi, cf, gR, gI, gG, bR, bI2, yr, yi);
        float m = __fadd_rn(__fmul_rn(yr, yr), __fmul_rn(yi, yi));
        if (m > bestm) { bestm = m; bestr = yr; besti = yi; }
      }
      size_t o = ((size_t)(n * 16 + c) * 32 + oy) * 32 + ox;
      Pr[o] = bestr;
      Pi[o] = besti;
    }
  }
}

// ---- weight repack: [co][ci][kk] -> [co][kk][ci] (for float4 cin loads)
__global__ __launch_bounds__(256) void repack_w(const float* __restrict__ src,
                                                float* __restrict__ dst,
                                                int CIN, int KK, int total) {
  int i = blockIdx.x * 256 + threadIdx.x;
  if (i >= total) return;
  int kk = i % KK;
  int rem = i / KK;
  int ci = rem % CIN;
  int co = rem / CIN;
  dst[((size_t)co * KK + kk) * CIN + ci] = src[i];
}

// ---- generic transpose: src[R][C] -> dst[C][R]
__global__ __launch_bounds__(256) void transpose_rc(const float* __restrict__ src,
                                                    float* __restrict__ dst,
                                                    int R, int C) {
  int i = blockIdx.x * 256 + threadIdx.x;
  if (i >= R * C) return;
  int r = i / C, c = i % C;
  dst[(size_t)c * R + r] = src[i];
}

// ============== band kernels (fallback L2 path) ===========================
#define STAGE_COMP(SRCBASE)                                          \
  {                                                                  \
    const float* src_ = (SRCBASE) + (size_t)n * CIN * HH;            \
    for (int idx = t; idx < RALLOC * H * CINQ; idx += NT) {          \
      int px = idx % (RALLOC * H);                                   \
      int cq = idx / (RALLOC * H);                                   \
      int lr = px / H, col = px - lr * H;                            \
      int gr = r0 + lr;                                              \
      if (gr < 0 || gr >= H) continue;                               \
      const float* sp = src_ + (size_t)cq * 4 * HH + gr * H + col;   \
      float4 v;                                                      \
      v.x = sp[0]; v.y = sp[HH]; v.z = sp[2 * HH]; v.w = sp[3 * HH]; \
      *(float4*)&sin_[(lr * W + col + PAD) * ST1 + cq * 4] = v;      \
    }                                                                \
  }

template <int H, int CIN, int COUT, int K, int PASS>
__global__ __launch_bounds__(COUT * 4, 2) void cconv_band_stats(
    const float* __restrict__ Xr, const float* __restrict__ Xi,
    const float* __restrict__ wrT, const float* __restrict__ wiT,
    const float* __restrict__ br, const float* __restrict__ bi,
    const float* __restrict__ coef, float* __restrict__ partial) {
  constexpr int HH = H * H;
  constexpr int PAD = K / 2, KK = K * K;
  constexpr int CLEN = (HH >= 128) ? 16 : 8;
  constexpr int NLEAF = HH / (8 * CLEN);
  constexpr int BROWS = (CLEN * 8) / H;
  constexpr int RALLOC = BROWS + 2 * PAD;
  constexpr int W = H + 2 * PAD;
  constexpr int ST1 = CIN + 4;
  constexpr int CINQ = CIN / 4;
  constexpr int NT = COUT * 4;
  constexpr int NC = COUT * 8;

  __shared__ __align__(16) float sin_[RALLOC * W * ST1];
  __shared__ float red0[NC], red1[NC], red2[PASS ? NC : 1];

  int b = blockIdx.x;
  int leaf = b % NLEAF;
  int n = b / NLEAF;
  int t = threadIdx.x;
  int r0 = leaf * BROWS - PAD;

  for (int i = t; i < RALLOC * W * ST1; i += NT) sin_[i] = 0.f;
  __syncthreads();
  STAGE_COMP(Xr)
  __syncthreads();

  int c0 = t >> 3, j = t & 7;
  int c1 = c0 + COUT / 2;
  const float* wrb0 = wrT + (size_t)c0 * CIN * KK;
  const float* wib0 = wiT + (size_t)c0 * CIN * KK;
  const float* wrb1 = wrT + (size_t)c1 * CIN * KK;
  const float* wib1 = wiT + (size_t)c1 * CIN * KK;

  float A0[CLEN], D0[CLEN], A1[CLEN], D1[CLEN];
  float B0[CLEN], C0_[CLEN], B1[CLEN], C1_[CLEN];
#pragma unroll
  for (int k = 0; k < CLEN; ++k) {
    A0[k] = 0.f; D0[k] = 0.f; A1[k] = 0.f; D1[k] = 0.f;
    B0[k] = 0.f; C0_[k] = 0.f; B1[k] = 0.f; C1_[k] = 0.f;
  }

#define STATS_TAPS(PH)                                                        \
  for (int ky = 0; ky < K; ++ky) {                                            \
    for (int kx = 0; kx < K; ++kx) {                                          \
      const float* tb = sin_ + (ky * W + kx + j) * ST1;                       \
      const float* wrp0 = wrb0 + (ky * K + kx) * CIN;                         \
      const float* wip0 = wib0 + (ky * K + kx) * CIN;                         \
      const float* wrp1 = wrb1 + (ky * K + kx) * CIN;                         \
      const float* wip1 = wib1 + (ky * K + kx) * CIN;                         \
      _Pragma("unroll 2") for (int cq = 0; cq < CINQ; ++cq) {                 \
        const float* tbc = tb + cq * 4;                                       \
        float4 wR0v = *(const float4*)(wrp0 + cq * 4);                        \
        float4 wI0v = *(const float4*)(wip0 + cq * 4);                        \
        float4 wR1v = *(const float4*)(wrp1 + cq * 4);                        \
        float4 wI1v = *(const float4*)(wip1 + cq * 4);                        \
        _Pragma("unroll") for (int k = 0; k < CLEN; ++k) {                    \
          float4 v4 = *(const float4*)(tbc +                                  \
              (((k * 8) / H) * W + ((k * 8) % H)) * ST1);                     \
          if (PH == 0) {                                                      \
            PFMA8(A0[k], D0[k], wR0v, wI0v)                                   \
            PFMA8(A1[k], D1[k], wR1v, wI1v)                                   \
          } else {                                                            \
            PFMA8(B0[k], C0_[k], wI0v, wR0v)                                  \
            PFMA8(B1[k], C1_[k], wI1v, wR1v)                                  \
          }                                                                   \
        }                                                                     \
      }                                                                       \
    }                                                                         \
  }

  STATS_TAPS(0)
  __syncthreads();
  STAGE_COMP(Xi)
  __syncthreads();
  STATS_TAPS(1)
#undef STATS_TAPS

  {  // c0 epilogue
    float cbR = br[c0], cbI = bi[c0];
    float mr = 0.f, mi = 0.f;
    if (PASS) { mr = coef[c0 * 5 + 0]; mi = coef[c0 * 5 + 1]; }
    float a0 = 0.f, a1 = 0.f, a2 = 0.f;
#pragma unroll
    for (int k = 0; k < CLEN; ++k) {
      float yr = __fsub_rn(__fadd_rn(A0[k], cbR), __fadd_rn(B0[k], cbI));
      float yi = __fadd_rn(__fadd_rn(C0_[k], cbR), __fadd_rn(D0[k], cbI));
      if (PASS == 0) {
        a0 = __fadd_rn(a0, yr);
        a1 = __fadd_rn(a1, yi);
      } else {
        float cr = __fsub_rn(yr, mr), ci = __fsub_rn(yi, mi);
        a0 = __fadd_rn(a0, __fmul_rn(cr, cr));
        a1 = __fadd_rn(a1, __fmul_rn(ci, ci));
        a2 = __fadd_rn(a2, __fmul_rn(cr, ci));
      }
    }
    red0[c0 * 8 + j] = a0; red1[c0 * 8 + j] = a1;
    if (PASS) red2[c0 * 8 + j] = a2;
  }
  {  // c1 epilogue
    float cbR = br[c1], cbI = bi[c1];
    float mr = 0.f, mi = 0.f;
    if (PASS) { mr = coef[c1 * 5 + 0]; mi = coef[c1 * 5 + 1]; }
    float a0 = 0.f, a1 = 0.f, a2 = 0.f;
#pragma unroll
    for (int k = 0; k < CLEN; ++k) {
      float yr = __fsub_rn(__fadd_rn(A1[k], cbR), __fadd_rn(B1[k], cbI));
      float yi = __fadd_rn(__fadd_rn(C1_[k], cbR), __fadd_rn(D1[k], cbI));
      if (PASS == 0) {
        a0 = __fadd_rn(a0, yr);
        a1 = __fadd_rn(a1, yi);
      } else {
        float cr = __fsub_rn(yr, mr), ci = __fsub_rn(yi, mi);
        a0 = __fadd_rn(a0, __fmul_rn(cr, cr));
        a1 = __fadd_rn(a1, __fmul_rn(ci, ci));
        a2 = __fadd_rn(a2, __fmul_rn(cr, ci));
      }
    }
    red0[c1 * 8 + j] = a0; red1[c1 * 8 + j] = a1;
    if (PASS) red2[c1 * 8 + j] = a2;
  }
  __syncthreads();
  if (j == 0) {
    constexpr int S = PASS ? 3 : 2;
#pragma unroll
    for (int s = 0; s < 2; ++s) {
      int cc = s ? c1 : c0;
      int o = cc * 8;
      size_t base = (((size_t)n * COUT + cc) * NLEAF + leaf) * S;
      partial[base + 0] =
          __fadd_rn(__fadd_rn(__fadd_rn(red0[o], red0[o + 1]), __fadd_rn(red0[o + 2], red0[o + 3])),
                    __fadd_rn(__fadd_rn(red0[o + 4], red0[o + 5]), __fadd_rn(red0[o + 6], red0[o + 7])));
      partial[base + 1] =
          __fadd_rn(__fadd_rn(__fadd_rn(red1[o], red1[o + 1]), __fadd_rn(red1[o + 2], red1[o + 3])),
                    __fadd_rn(__fadd_rn(red1[o + 4], red1[o + 5]), __fadd_rn(red1[o + 6], red1[o + 7])));
      if (PASS)
        partial[base + 2] =
            __fadd_rn(__fadd_rn(__fadd_rn(red2[o], red2[o + 1]), __fadd_rn(red2[o + 2], red2[o + 3])),
                      __fadd_rn(__fadd_rn(red2[o + 4], red2[o + 5]), __fadd_rn(red2[o + 6], red2[o + 7])));
    }
  }
}

template <int H, int CIN, int COUT, int K, int OBR>
__global__ __launch_bounds__(COUT * 4, 2) void cconv_band_pool(
    const float* __restrict__ Xr, const float* __restrict__ Xi,
    const float* __restrict__ wrT, const float* __restrict__ wiT,
    const float* __restrict__ br, const float* __restrict__ bi,
    const float* __restrict__ coef, const float* __restrict__ grr,
    const float* __restrict__ gri, const float* __restrict__ gii,
    const float* __restrict__ bbr, const float* __restrict__ bbi,
    float* __restrict__ Pr, float* __restrict__ Pi) {
  constexpr int HH = H * H;
  constexpr int OH = H / 2;
  constexpr int NBAND = OH / OBR;
  constexpr int PAD = K / 2, KK = K * K;
  constexpr int CROWS = OBR * 2;
  constexpr int RALLOC = CROWS + 2 * PAD;
  constexpr int W = H + 2 * PAD;
  constexpr int ST1 = CIN + 4;
  constexpr int CINQ = CIN / 4;
  constexpr int NT = COUT * 4;
  constexpr int NOUT = (OBR * OH) / 8;
  constexpr int NQ = NOUT * 4;

  __shared__ __align__(16) float sin_[RALLOC * W * ST1];

  int b = blockIdx.x;
  int band = b % NBAND;
  int n = b / NBAND;
  int t = threadIdx.x;
  int r0 = band * CROWS - PAD;

  for (int i = t; i < RALLOC * W * ST1; i += NT) sin_[i] = 0.f;
  __syncthreads();
  STAGE_COMP(Xr)
  __syncthreads();

  int c0 = t >> 3, j = t & 7;
  int c1 = c0 + COUT / 2;
  const float* jbp = sin_ + (2 * (j / OH) * W + 2 * (j % OH)) * ST1;
  const float* wrb0 = wrT + (size_t)c0 * CIN * KK;
  const float* wib0 = wiT + (size_t)c0 * CIN * KK;
  const float* wrb1 = wrT + (size_t)c1 * CIN * KK;
  const float* wib1 = wiT + (size_t)c1 * CIN * KK;

  float A0[NQ], D0[NQ], A1[NQ], D1[NQ];
  float B0[NQ], C0_[NQ], B1[NQ], C1_[NQ];
#pragma unroll
  for (int q = 0; q < NQ; ++q) {
    A0[q] = 0.f; D0[q] = 0.f; A1[q] = 0.f; D1[q] = 0.f;
    B0[q] = 0.f; C0_[q] = 0.f; B1[q] = 0.f; C1_[q] = 0.f;
  }

#define POOL_TAPS(PH)                                                         \
  for (int ky = 0; ky < K; ++ky) {                                            \
    for (int kx = 0; kx < K; ++kx) {                                          \
      const float* tb = jbp + (ky * W + kx) * ST1;                            \
      const float* wrp0 = wrb0 + (ky * K + kx) * CIN;                         \
      const float* wip0 = wib0 + (ky * K + kx) * CIN;                         \
      const float* wrp1 = wrb1 + (ky * K + kx) * CIN;                         \
      const float* wip1 = wib1 + (ky * K + kx) * CIN;                         \
      _Pragma("unroll 2") for (int cq = 0; cq < CINQ; ++cq) {                 \
        const float* tbc = tb + cq * 4;                                       \
        float4 wR0v = *(const float4*)(wrp0 + cq * 4);                        \
        float4 wI0v = *(const float4*)(wip0 + cq * 4);                        \
        float4 wR1v = *(const float4*)(wrp1 + cq * 4);                        \
        float4 wI1v = *(const float4*)(wip1 + cq * 4);                        \
        _Pragma("unroll") for (int q = 0; q < NQ; ++q) {                      \
          float4 v4 = *(const float4*)(tbc +                                  \
              ((2 * ((8 * (q >> 2)) / OH) + ((q & 3) >> 1)) * W +             \
               2 * ((8 * (q >> 2)) % OH) + ((q & 3) & 1)) * ST1);             \
          if (PH == 0) {                                                      \
            PFMA8(A0[q], D0[q], wR0v, wI0v)                                   \
            PFMA8(A1[q], D1[q], wR1v, wI1v)                                   \
          } else {                                                            \
            PFMA8(B0[q], C0_[q], wI0v, wR0v)                                  \
            PFMA8(B1[q], C1_[q], wI1v, wR1v)                                  \
          }                                                                   \
        }                                                                     \
      }                                                                       \
    }                                                                         \
  }

  POOL_TAPS(0)
  __syncthreads();
  STAGE_COMP(Xi)
  __syncthreads();
  POOL_TAPS(1)
#undef POOL_TAPS

  {  // c0 epilogue
    float cbR = br[c0], cbI = bi[c0];
    const float* cf = coef + c0 * 5;
    float gR = grr[c0], gI = gri[c0], gG = gii[c0], bR = bbr[c0], bI2 = bbi[c0];
#pragma unroll
    for (int u = 0; u < NOUT; ++u) {
      int e = j + 8 * u;
      int oy = band * OBR + e / OH, ox = e % OH;
      float bestr = 0.f, besti = 0.f, bestm = -1.f;
#pragma unroll
      for (int p = 0; p < 4; ++p) {
        int q = u * 4 + p;
        float xr = __fsub_rn(__fadd_rn(A0[q], cbR), __fadd_rn(B0[q], cbI));
        float xi = __fadd_rn(__fadd_rn(C0_[q], cbR), __fadd_rn(D0[q], cbI));
        float yr, yi;
        bn_apply_f32(xr, xi, cf, gR, gI, gG, bR, bI2, yr, yi);
        float m = __fadd_rn(__fmul_rn(yr, yr), __fmul_rn(yi, yi));
        if (m > bestm) { bestm = m; bestr = yr; besti = yi; }
      }
      size_t o = ((size_t)(n * COUT + c0) * OH + oy) * OH + ox;
      Pr[o] = bestr;
      Pi[o] = besti;
    }
  }
  {  // c1 epilogue
    float cbR = br[c1], cbI = bi[c1];
    const float* cf = coef + c1 * 5;
    float gR = grr[c1], gI = gri[c1], gG = gii[c1], bR = bbr[c1], bI2 = bbi[c1];
#pragma unroll
    for (int u = 0; u < NOUT; ++u) {
      int e = j + 8 * u;
      int oy = band * OBR + e / OH, ox = e % OH;
      float bestr = 0.f, besti = 0.f, bestm = -1.f;
#pragma unroll
      for (int p = 0; p < 4; ++p) {
        int q = u * 4 + p;
        float xr = __fsub_rn(__fadd_rn(A1[q], cbR), __fadd_rn(B1[q], cbI));
        float xi = __fadd_rn(__fadd_rn(C1_[q], cbR), __fadd_rn(D1[q], cbI));
        float yr, yi;
        bn_apply_f32(xr, xi, cf, gR, gI, gG, bR, bI2, yr, yi);
        float m = __fadd_rn(__fmul_rn(yr, yr), __fmul_rn(yi, yi));
        if (m > bestm) { bestm = m; bestr = yr; besti = yi; }
      }
      size_t o = ((size_t)(n * COUT + c1) * OH + oy) * OH + ox;
      Pr[o] = bestr;
      Pi[o] = besti;
    }
  }
}

// ============== store-once path: conv -> buf, then stream passes ===========
// 2-channel store (used for the big L2 store and NEED2 fallback tier).
template <int H, int CIN, int COUT, int CG, int K, int REPS>
__global__ __launch_bounds__((CG / 2) * 8 * REPS, 2) void cconv_band_store(
    const float* __restrict__ Xr, const float* __restrict__ Xi,
    const float* __restrict__ wrT, const float* __restrict__ wiT,
    const float* __restrict__ br, const float* __restrict__ bi,
    int coff, float* __restrict__ bufR, float* __restrict__ bufI) {
  constexpr int HH = H * H;
  constexpr int PAD = K / 2, KK = K * K;
  constexpr int CLEN = (HH >= 128) ? 16 : 8;
  constexpr int NLEAF = HH / (8 * CLEN);
  constexpr int BROWS = (CLEN * 8) / H;
  constexpr int RALLOC = BROWS + 2 * PAD;
  constexpr int W = H + 2 * PAD;
  constexpr int ST1 = CIN + 4;
  constexpr int CINQ = CIN / 4;
  constexpr int CPAIR = CG / 2;
  constexpr int NT = CPAIR * 8 * REPS;
  constexpr int CLT = CLEN / REPS;           // k per thread
  constexpr int RROWS = (CLT * 8) / H;       // rows per replica (REPS>1)

  __shared__ __align__(16) float sin_[RALLOC * W * ST1];

  int b = blockIdx.x;
  int leaf = b % NLEAF;
  int n = b / NLEAF;
  int t = threadIdx.x;
  int r0 = leaf * BROWS - PAD;

  for (int i = t; i < RALLOC * W * ST1; i += NT) sin_[i] = 0.f;
  __syncthreads();
  STAGE_COMP(Xr)
  __syncthreads();

  int rep = t / (CPAIR * 8);
  int tt = t % (CPAIR * 8);
  int c0l = tt >> 3, j = tt & 7;
  int c0 = coff + c0l, c1 = c0 + CPAIR;
  const float* jbp = sin_ + ((REPS > 1 ? rep * RROWS : 0) * W + j) * ST1;
  const float* wrb0 = wrT + (size_t)c0 * CIN * KK;
  const float* wib0 = wiT + (size_t)c0 * CIN * KK;
  const float* wrb1 = wrT + (size_t)c1 * CIN * KK;
  const float* wib1 = wiT + (size_t)c1 * CIN * KK;

  float A0[CLT], D0[CLT], A1[CLT], D1[CLT];
  float B0[CLT], C0_[CLT], B1[CLT], C1_[CLT];
#pragma unroll
  for (int k = 0; k < CLT; ++k) {
    A0[k] = 0.f; D0[k] = 0.f; A1[k] = 0.f; D1[k] = 0.f;
    B0[k] = 0.f; C0_[k] = 0.f; B1[k] = 0.f; C1_[k] = 0.f;
  }

#define STORE_TAPS(PH)                                                        \
  for (int ky = 0; ky < K; ++ky) {                                            \
    for (int kx = 0; kx < K; ++kx) {                                          \
      const float* tb = jbp + (ky * W + kx) * ST1;                            \
      const float* wrp0 = wrb0 + (ky * K + kx) * CIN;                         \
      const float* wip0 = wib0 + (ky * K + kx) * CIN;                         \
      const float* wrp1 = wrb1 + (ky * K + kx) * CIN;                         \
      const float* wip1 = wib1 + (ky * K + kx) * CIN;                         \
      _Pragma("unroll 2") for (int cq = 0; cq < CINQ; ++cq) {                 \
        const float* tbc = tb + cq * 4;                                       \
        float4 wR0v = *(const float4*)(wrp0 + cq * 4);                        \
        float4 wI0v = *(const float4*)(wip0 + cq * 4);                        \
        float4 wR1v = *(const float4*)(wrp1 + cq * 4);                        \
        float4 wI1v = *(const float4*)(wip1 + cq * 4);                        \
        _Pragma("unroll") for (int k = 0; k < CLT; ++k) {                     \
          float4 v4 = *(const float4*)(tbc +                                  \
              (((k * 8) / H) * W + ((k * 8) % H)) * ST1);                     \
          if (PH == 0) {                                                      \
            PFMA8(A0[k], D0[k], wR0v, wI0v)                                   \
            PFMA8(A1[k], D1[k], wR1v, wI1v)                                   \
          } else {                                                            \
            PFMA8(B0[k], C0_[k], wI0v, wR0v)                                  \
            PFMA8(B1[k], C1_[k], wI1v, wR1v)                                  \
          }                                                                   \
        }                                                                     \
      }                                                                       \
    }                                                                         \
  }

  STORE_TAPS(0)
  __syncthreads();
  STAGE_COMP(Xi)
  __syncthreads();
  STORE_TAPS(1)
#undef STORE_TAPS

  float cbR0 = br[c0], cbI0 = bi[c0];
  float cbR1 = br[c1], cbI1 = bi[c1];
  size_t b0 = ((size_t)n * CG + c0l) * HH;
  size_t b1 = ((size_t)n * CG + (c0l + CPAIR)) * HH;
#pragma unroll
  for (int k = 0; k < CLT; ++k) {
    int px = leaf * CLEN * 8 + (rep * CLT + k) * 8 + j;
    float yr0 = __fsub_rn(__fadd_rn(A0[k], cbR0), __fadd_rn(B0[k], cbI0));
    float yi0 = __fadd_rn(__fadd_rn(C0_[k], cbR0), __fadd_rn(D0[k], cbI0));
    bufR[b0 + px] = yr0;
    bufI[b0 + px] = yi0;
    float yr1 = __fsub_rn(__fadd_rn(A1[k], cbR1), __fadd_rn(B1[k], cbI1));
    float yi1 = __fadd_rn(__fadd_rn(C1_[k], cbR1), __fadd_rn(D1[k], cbI1));
    bufR[b1 + px] = yr1;
    bufI[b1 + px] = yi1;
  }
}

// 4-channel store (L3/L4 where K=3 makes weight reload cheap).
template <int H, int CIN, int COUT, int CG, int K, int REPS>
__global__ __launch_bounds__((CG / 4) * 8 * REPS, 2) void cconv_band_store4(
    const float* __restrict__ Xr, const float* __restrict__ Xi,
    const float* __restrict__ wrT, const float* __restrict__ wiT,
    const float* __restrict__ br, const float* __restrict__ bi,
    int coff, float* __restrict__ bufR, float* __restrict__ bufI) {
  constexpr int HH = H * H;
  constexpr int PAD = K / 2, KK = K * K;
  constexpr int CLEN = (HH >= 128) ? 16 : 8;
  constexpr int NLEAF = HH / (8 * CLEN);
  constexpr int BROWS = (CLEN * 8) / H;
  constexpr int RALLOC = BROWS + 2 * PAD;
  constexpr int W = H + 2 * PAD;
  constexpr int ST1 = CIN + 4;
  constexpr int CINQ = CIN / 4;
  constexpr int CQ = CG / 4;                 // channel lanes
  constexpr int NT = CQ * 8 * REPS;
  constexpr int CLT = CLEN / REPS;           // k per thread
  constexpr int RROWS = (CLT * 8) / H;       // rows per replica

  __shared__ __align__(16) float sin_[RALLOC * W * ST1];

  int b = blockIdx.x;
  int leaf = b % NLEAF;
  int n = b / NLEAF;
  int t = threadIdx.x;
  int r0 = leaf * BROWS - PAD;

  for (int i = t; i < RALLOC * W * ST1; i += NT) sin_[i] = 0.f;
  __syncthreads();
  STAGE_COMP(Xr)
  __syncthreads();

  int rep = t / (CQ * 8);
  int tt = t % (CQ * 8);
  int c0l = tt >> 3, j = tt & 7;
  const float* jbp = sin_ + ((REPS > 1 ? rep * RROWS : 0) * W + j) * ST1;
  const float* wrb[4];
  const float* wib[4];
#pragma unroll
  for (int ch = 0; ch < 4; ++ch) {
    int c = coff + c0l + ch * CQ;
    wrb[ch] = wrT + (size_t)c * CIN * KK;
    wib[ch] = wiT + (size_t)c * CIN * KK;
  }

  float A[4][CLT], Bq[4][CLT], Cc[4][CLT], D[4][CLT];
#pragma unroll
  for (int ch = 0; ch < 4; ++ch)
#pragma unroll
    for (int k = 0; k < CLT; ++k) {
      A[ch][k] = 0.f; Bq[ch][k] = 0.f; Cc[ch][k] = 0.f; D[ch][k] = 0.f;
    }

#define STORE4_TAPS(PH)                                                       \
  for (int ky = 0; ky < K; ++ky) {                                            \
    for (int kx = 0; kx < K; ++kx) {                                          \
      const float* tb = jbp + (ky * W + kx) * ST1;                            \
      int woff = (ky * K + kx) * CIN;                                         \
      _Pragma("unroll 2") for (int cq = 0; cq < CINQ; ++cq) {                 \
        const float* tbc = tb + cq * 4;                                       \
        float4 wRv[4], wIv[4];                                                \
        _Pragma("unroll") for (int ch = 0; ch < 4; ++ch) {                    \
          wRv[ch] = *(const float4*)(wrb[ch] + woff + cq * 4);                \
          wIv[ch] = *(const float4*)(wib[ch] + woff + cq * 4);                \
        }                                                                     \
        _Pragma("unroll") for (int k = 0; k < CLT; ++k) {                     \
          float4 v4 = *(const float4*)(tbc +                                  \
              (((k * 8) / H) * W + ((k * 8) % H)) * ST1);                     \
          if (PH == 0) {                                                      \
            PFMA8(A[0][k], D[0][k], wRv[0], wIv[0])                           \
            PFMA8(A[1][k], D[1][k], wRv[1], wIv[1])                           \
            PFMA8(A[2][k], D[2][k], wRv[2], wIv[2])                           \
            PFMA8(A[3][k], D[3][k], wRv[3], wIv[3])                           \
          } else {                                                            \
            PFMA8(Bq[0][k], Cc[0][k], wIv[0], wRv[0])                         \
            PFMA8(Bq[1][k], Cc[1][k], wIv[1], wRv[1])                         \
            PFMA8(Bq[2][k], Cc[2][k], wIv[2], wRv[2])                         \
            PFMA8(Bq[3][k], Cc[3][k], wIv[3], wRv[3])                         \
          }                                                                   \
        }                                                                     \
      }                                                                       \
    }                                                                         \
  }

  STORE4_TAPS(0)
  __syncthreads();
  STAGE_COMP(Xi)
  __syncthreads();
  STORE4_TAPS(1)
#undef STORE4_TAPS

#pragma unroll
  for (int ch = 0; ch < 4; ++ch) {
    int c = coff + c0l + ch * CQ;
    float cbR = br[c], cbI = bi[c];
    size_t bbase = ((size_t)n * CG + (c0l + ch * CQ)) * HH;
#pragma unroll
    for (int k = 0; k < CLT; ++k) {
      int px = leaf * CLEN * 8 + (rep * CLT + k) * 8 + j;
      float yr = __fsub_rn(__fadd_rn(A[ch][k], cbR), __fadd_rn(Bq[ch][k], cbI));
      float yi = __fadd_rn(__fadd_rn(Cc[ch][k], cbR), __fadd_rn(D[ch][k], cbI));
      bufR[bbase + px] = yr;
      bufI[bbase + px] = yi;
    }
  }
}

// Stream stats: reads stored conv, sums in the EXACT chain order (leaf,j,k),
// same leaf-pair reduce, same partial layout (C=CG local channels).
template <int CG, int HH, int CLEN, int PASS>
__global__ __launch_bounds__(CG * 8) void cstats_stream(
    const float* __restrict__ bufR, const float* __restrict__ bufI,
    const float* __restrict__ coef, float* __restrict__ partial, int coff) {
  constexpr int NLEAF = HH / (8 * CLEN);
  constexpr int NT = CG * 8;
  __shared__ float red0[NT], red1[NT], red2[PASS ? NT : 1];
  int b = blockIdx.x;
  int leaf = b % NLEAF;
  int n = b / NLEAF;
  int t = threadIdx.x;
  int cl = t >> 3, j = t & 7;
  int c = coff + cl;
  size_t base = ((size_t)n * CG + cl) * HH + leaf * CLEN * 8 + j;
  float mr = 0.f, mi = 0.f;
  if (PASS) { mr = coef[c * 5 + 0]; mi = coef[c * 5 + 1]; }
  float a0 = 0.f, a1 = 0.f, a2 = 0.f;
#pragma unroll
  for (int k = 0; k < CLEN; ++k) {
    float yr = bufR[base + k * 8];
    float yi = bufI[base + k * 8];
    if (PASS == 0) {
      a0 = __fadd_rn(a0, yr);
      a1 = __fadd_rn(a1, yi);
    } else {
      float cr = __fsub_rn(yr, mr), ci = __fsub_rn(yi, mi);
      a0 = __fadd_rn(a0, __fmul_rn(cr, cr));
      a1 = __fadd_rn(a1, __fmul_rn(ci, ci));
      a2 = __fadd_rn(a2, __fmul_rn(cr, ci));
    }
  }
  red0[t] = a0; red1[t] = a1; if (PASS) red2[t] = a2;
  __syncthreads();
  if (j == 0) {
    constexpr int S = PASS ? 3 : 2;
    int o = cl * 8;
    size_t pb = (((size_t)n * CG + cl) * NLEAF + leaf) * S;
    partial[pb + 0] =
        __fadd_rn(__fadd_rn(__fadd_rn(red0[o], red0[o + 1]), __fadd_rn(red0[o + 2], red0[o + 3])),
                  __fadd_rn(__fadd_rn(red0[o + 4], red0[o + 5]), __fadd_rn(red0[o + 6], red0[o + 7])));
    partial[pb + 1] =
        __fadd_rn(__fadd_rn(__fadd_rn(red1[o], red1[o + 1]), __fadd_rn(red1[o + 2], red1[o + 3])),
                  __fadd_rn(__fadd_rn(red1[o + 4], red1[o + 5]), __fadd_rn(red1[o + 6], red1[o + 7])));
    if (PASS)
      partial[pb + 2] =
          __fadd_rn(__fadd_rn(__fadd_rn(red2[o], red2[o + 1]), __fadd_rn(red2[o + 2], red2[o + 3])),
                    __fadd_rn(__fadd_rn(red2[o + 4], red2[o + 5]), __fadd_rn(red2[o + 6], red2[o + 7])));
  }
}

// Stream pool: reads stored conv, BN+argmax in the exact candidate order.
template <int CG, int H, int COUT>
__global__ __launch_bounds__(256) void cpool_stream(
    const float* __restrict__ bufR, const float* __restrict__ bufI,
    const float* __restrict__ coef, const float* __restrict__ grr,
    const float* __restrict__ gri, const float* __restrict__ gii,
    const float* __restrict__ bbr, const float* __restrict__ bbi,
    float* __restrict__ Pr, float* __restrict__ Pi, int coff) {
  constexpr int OH = H / 2, OHH = OH * OH, HH = H * H;
  int n = blockIdx.x;
  for (int idx = threadIdx.x; idx < CG * OHH; idx += 256) {
    int cl = idx / OHH, q = idx % OHH;
    int oy = q / OH, ox = q % OH;
    int c = coff + cl;
    size_t base = ((size_t)n * CG + cl) * HH;
    const float* cf = coef + c * 5;
    float gR = grr[c], gI = gri[c], gG = gii[c], bR = bbr[c], bI2 = bbi[c];
    float bestr = 0.f, besti = 0.f, bestm = -1.f;
#pragma unroll
    for (int p = 0; p < 4; ++p) {
      size_t o = base + (size_t)(2 * oy + (p >> 1)) * H + 2 * ox + (p & 1);
      float xr = bufR[o], xi = bufI[o];
      float yr, yi;
      bn_apply_f32(xr, xi, cf, gR, gI, gG, bR, bI2, yr, yi);
      float m = __fadd_rn(__fmul_rn(yr, yr), __fmul_rn(yi, yi));
      if (m > bestm) { bestm = m; bestr = yr; besti = yi; }
    }
    size_t o = ((size_t)(n * COUT + c) * OH + oy) * OH + ox;
    Pr[o] = bestr;
    Pi[o] = besti;
  }
}

// ---- combine over n (sequential fp32, numpy outer-axis order), then coef.
template <int C, int NLEAF, int TPB>
__global__ __launch_bounds__(TPB) void np_mean_combine3(
    const float* __restrict__ partial, float* __restrict__ coef, float Mf,
    int coff) {
  int t = threadIdx.x;
  if (t >= C * 2) return;
  int c = t >> 1, s = t & 1;
  float acc = 0.f;
  for (int n = 0; n < 512; ++n) {
    const float* p = partial + (((size_t)n * C + c) * NLEAF) * 2 + s;
    float v;
    if (NLEAF == 8)
      v = __fadd_rn(__fadd_rn(__fadd_rn(p[0], p[2]), __fadd_rn(p[4], p[6])),
                    __fadd_rn(__fadd_rn(p[8], p[10]), __fadd_rn(p[12], p[14])));
    else if (NLEAF == 2)
      v = __fadd_rn(p[0], p[2]);
    else
      v = p[0];
    acc = __fadd_rn(acc, v);
  }
  coef[(coff + c) * 5 + s] = __fdiv_rn(acc, Mf);
}

template <int C, int NLEAF, int TPB>
__global__ __launch_bounds__(TPB) void np_cov_combine3(
    const float* __restrict__ partial, float* __restrict__ coef, float Mf,
    int coff) {
  __shared__ float sums[C * 3];
  int t = threadIdx.x;
  if (t < C * 3) {
    int c = t / 3, s = t % 3;
    float acc = 0.f;
    for (int n = 0; n < 512; ++n) {
      const float* p = partial + (((size_t)n * C + c) * NLEAF) * 3 + s;
      float v;
      if (NLEAF == 8)
        v = __fadd_rn(__fadd_rn(__fadd_rn(p[0], p[3]), __fadd_rn(p[6], p[9])),
                      __fadd_rn(__fadd_rn(p[12], p[15]), __fadd_rn(p[18], p[21])));
      else if (NLEAF == 2)
        v = __fadd_rn(p[0], p[3]);
      else
        v = p[0];
      acc = __fadd_rn(acc, v);
    }
    sums[c * 3 + s] = acc;
  }
  __syncthreads();
  if (t < C) {
    float Crr = __fadd_rn(__fdiv_rn(sums[t * 3 + 0], Mf), 1e-5f);
    float Cii = __fadd_rn(__fdiv_rn(sums[t * 3 + 1], Mf), 1e-5f);
    float Cri = __fdiv_rn(sums[t * 3 + 2], Mf);
    float s_ = __fsqrt_rn(__fsub_rn(__fmul_rn(Crr, Cii), __fmul_rn(Cri, Cri)));
    float t_ = __fsqrt_rn(__fadd_rn(__fadd_rn(Crr, Cii), __fmul_rn(2.f, s_)));
    float inv = __fdiv_rn(1.f, __fmul_rn(s_, t_));
    int cg = coff + t;
    coef[cg * 5 + 2] = __fmul_rn(__fadd_rn(Cii, s_), inv);   // Rrr
    coef[cg * 5 + 3] = __fmul_rn(__fadd_rn(Crr, s_), inv);   // Rii
    coef[cg * 5 + 4] = __fmul_rn(-Cri, inv);                 // Rri
  }
}

// ---------------- fused FC head (fp64 accumulate; transposed weights)
__global__ __launch_bounds__(256) void fc_head_kernel(
    const float* __restrict__ Fr, const float* __restrict__ Fi,
    const float* __restrict__ wrT, const float* __restrict__ wiT,
    const float* __restrict__ br, const float* __restrict__ bi,
    const float* __restrict__ w2T, const float* __restrict__ b2,
    float* __restrict__ logits, float* __restrict__ er_out,
    float* __restrict__ ei_out) {
  int n = blockIdx.x, t = threadIdx.x;
  __shared__ float sFr[1024], sFi[1024];
  __shared__ double sMag[256];
  for (int idx = t; idx < 1024; idx += 256) {
    sFr[idx] = Fr[(size_t)n * 1024 + idx];
    sFi[idx] = Fi[(size_t)n * 1024 + idx];
  }
  __syncthreads();
  {
    double er = 0.0, ei = 0.0;
    for (int k = 0; k < 1024; ++k) {
      double fx = (double)sFr[k], fy = (double)sFi[k];
      double a = (double)wrT[(size_t)k * 256 + t];
      double bb = (double)wiT[(size_t)k * 256 + t];
      er += fx * a - fy * bb;
      ei += fy * a + fx * bb;
    }
    double bR = (double)br[t], bI = (double)bi[t];
    er = fmax(er + (bR - bI), 0.0);
    ei = fmax(ei + (bR + bI), 0.0);
    er_out[(size_t)n * 256 + t] = (float)er;
    ei_out[(size_t)n * 256 + t] = (float)ei;
    sMag[t] = sqrt(er * er + ei * ei + 1e-12);
  }
  __syncthreads();
#pragma unroll
  for (int j = 0; j < 4; ++j) {
    int o = j * 256 + t;
    if (o < 1000) {
      double acc = 0.0;
      for (int k = 0; k < 256; ++k)
        acc += sMag[k] * (double)w2T[(size_t)k * 1000 + o];
      logits[(size_t)n * 1000 + o] = (float)(acc + (double)b2[o]);
    }
  }
}

// ---------------- launch
extern "C" void kernel_launch(void* const* d_in, const int* in_sizes, int n_in,
                              void* d_out, int out_size, void* d_ws,
                              size_t ws_size, hipStream_t stream) {
  (void)in_sizes; (void)n_in;
  const float* x = (const float*)d_in[0];
  const float* c1_wr = (const float*)d_in[1];
  const float* c1_wi = (const float*)d_in[2];
  const float* c1_br = (const float*)d_in[3];
  const float* c1_bi = (const float*)d_in[4];
  const float* c2_wr = (const float*)d_in[5];
  const float* c2_wi = (const float*)d_in[6];
  const float* c2_br = (const float*)d_in[7];
  const float* c2_bi = (const float*)d_in[8];
  const float* c3_wr = (const float*)d_in[9];
  const float* c3_wi = (const float*)d_in[10];
  const float* c3_br = (const float*)d_in[11];
  const float* c3_bi = (const float*)d_in[12];
  const float* c4_wr = (const float*)d_in[13];
  const float* c4_wi = (const float*)d_in[14];
  const float* c4_br = (const float*)d_in[15];
  const float* c4_bi = (const float*)d_in[16];
  const float* b1_grr = (const float*)d_in[17];
  const float* b1_gri = (const float*)d_in[18];
  const float* b1_gii = (const float*)d_in[19];
  const float* b1_br = (const float*)d_in[20];
  const float* b1_bi = (const float*)d_in[21];
  const float* b2_grr = (const float*)d_in[22];
  const float* b2_gri = (const float*)d_in[23];
  const float* b2_gii = (const float*)d_in[24];
  const float* b2_br = (const float*)d_in[25];
  const float* b2_bi = (const float*)d_in[26];
  const float* b3_grr = (const float*)d_in[27];
  const float* b3_gri = (const float*)d_in[28];
  const float* b3_gii = (const float*)d_in[29];
  const float* b3_br = (const float*)d_in[30];
  const float* b3_bi = (const float*)d_in[31];
  const float* b4_grr = (const float*)d_in[32];
  const float* b4_gri = (const float*)d_in[33];
  const float* b4_gii = (const float*)d_in[34];
  const float* b4_br = (const float*)d_in[35];
  const float* b4_bi = (const float*)d_in[36];
  const float* fc1_wr = (const float*)d_in[37];
  const float* fc1_wi = (const float*)d_in[38];
  const float* fc1_br = (const float*)d_in[39];
  const float* fc1_bi = (const float*)d_in[40];
  const float* fc2_w = (const float*)d_in[41];
  const float* fc2_b = (const float*)d_in[42];

  float* outL = (float*)d_out;
  float* er = outL + 512 * 1000;
  float* ei = er + 512 * 256;

  // Workspace tiers:
  //   NEED  (101,057,792): base layout (proven).
  //   NEED2 (135,005,440): +L2 store-once CG=8 (buf2 16.8M x2 + partial).
  //   NEED3 (236,848,384): +L2 store-once CG=32 single group (buf2 67M x2).
  const size_t NEED = 101057792;
  const size_t NEED2 = 135005440;
  const size_t NEED3 = 236848384;
  if (ws_size < NEED) {
    fill_kernel<<<(out_size + 255) / 256, 256, 0, stream>>>(
        (float*)d_out, out_size, (float)(ws_size >> 20));
    return;
  }
  const bool big3 = (ws_size >= NEED3);
  const bool big = (ws_size >= NEED2);
  char* w = (char*)d_ws;
  float* P1r = (float*)(w + 0);
  float* P1i = (float*)(w + 33554432);
  float* P2r = (float*)(w + 67108864);
  float* P2i = (float*)(w + 83886080);
  float* P3r = (float*)(w + 0);
  float* P3i = (float*)(w + 8388608);
  float* P4r = (float*)(w + 16777216);
  float* P4i = (float*)(w + 18874368);
  float* partialT = (float*)(w + 100663296);
  float* partial2 = (float*)(w + 67108864);   // fallback L2 leaf partials
  float* coef = (float*)(w + 101056512);
  float* c2_wrT = (float*)(w + 100663296);
  float* c2_wiT = (float*)(w + 100663296 + 51200);
  float* c3_wrT = (float*)(w + 100663296);
  float* c3_wiT = (float*)(w + 100663296 + 73728);
  float* c4_wrT = (float*)(w + 20971520);
  float* c4_wiT = (float*)(w + 20971520 + 147456);
  float* fc1_wrT = (float*)(w + 33554432);
  float* fc1_wiT = (float*)(w + 34603008);
  float* fc2_wT = (float*)(w + 35651584);
  float* buf3R = (float*)(w + 16777216);
  float* buf3I = (float*)(w + 33554432);
  float* partial3s = (float*)(w + 50331648);
  float* buf4R = (float*)(w + 67108864);
  float* buf4I = (float*)(w + 75497472);
  // NEED2 tier (CG=8): buf2 @101,057,792 / @117,835,008; partial @134,612,224
  float* buf2R = (float*)(w + 101057792);
  float* buf2I = (float*)(w + 117835008);
  float* partial2g = (float*)(w + 134612224);
  // NEED3 tier (CG=32): buf2 @101,057,792 (67M) / @168,166,656 (67M);
  //   partial @235,275,520 (1,572,864)
  float* buf2R3 = (float*)(w + 101057792);
  float* buf2I3 = (float*)(w + 168166656);
  float* partial2g3 = (float*)(w + 235275520);

  // ---- layer 1 (C=16, M=2097152) — recompute path (proven best)
  conv1_stats2<0><<<2048, 256, 0, stream>>>(x, c1_wr, c1_wi, c1_br, c1_bi,
                                            coef, partialT);
  np_mean_combine3<16, 1, 64><<<1, 64, 0, stream>>>(partialT, coef, 2097152.f, 0);
  conv1_stats2<1><<<2048, 256, 0, stream>>>(x, c1_wr, c1_wi, c1_br, c1_bi,
                                            coef, partialT);
  np_cov_combine3<16, 1, 64><<<1, 64, 0, stream>>>(partialT, coef, 2097152.f, 0);
  conv1_pool2<<<2048, 256, 0, stream>>>(x, c1_wr, c1_wi, c1_br, c1_bi, coef,
                                        b1_grr, b1_gri, b1_gii, b1_br, b1_bi,
                                        P1r, P1i);

  // ---- layer 2 (H=32, CIN=16, COUT=32, K=5, M=524288)
  repack_w<<<50, 256, 0, stream>>>(c2_wr, c2_wrT, 16, 25, 12800);
  repack_w<<<50, 256, 0, stream>>>(c2_wi, c2_wiT, 16, 25, 12800);
  if (big3) {
    // single group, CG=32, 2-channel/thread store (256 threads, proven R8)
    cconv_band_store<32, 16, 32, 32, 5, 2><<<4096, 256, 0, stream>>>(
        P1r, P1i, c2_wrT, c2_wiT, c2_br, c2_bi, 0, buf2R3, buf2I3);
    cstats_stream<32, 1024, 16, 0><<<4096, 256, 0, stream>>>(
        buf2R3, buf2I3, coef, partial2g3, 0);
    np_mean_combine3<32, 8, 64><<<1, 64, 0, stream>>>(partial2g3, coef,
                                                      524288.f, 0);
    cstats_stream<32, 1024, 16, 1><<<4096, 256, 0, stream>>>(
        buf2R3, buf2I3, coef, partial2g3, 0);
    np_cov_combine3<32, 8, 128><<<1, 128, 0, stream>>>(partial2g3, coef,
                                                       524288.f, 0);
    cpool_stream<32, 32, 32><<<512, 256, 0, stream>>>(
        buf2R3, buf2I3, coef, b2_grr, b2_gri, b2_gii, b2_br, b2_bi, P2r, P2i,
        0);
  } else if (big) {
    // 4 channel-groups of 8, REPS=4 (128-thread store)
    for (int g = 0; g < 4; ++g) {
      cconv_band_store<32, 16, 32, 8, 5, 4><<<4096, 128, 0, stream>>>(
          P1r, P1i, c2_wrT, c2_wiT, c2_br, c2_bi, g * 8, buf2R, buf2I);
      cstats_stream<8, 1024, 16, 0><<<4096, 64, 0, stream>>>(
          buf2R, buf2I, coef, partial2g, g * 8);
      np_mean_combine3<8, 8, 64><<<1, 64, 0, stream>>>(partial2g, coef,
                                                       524288.f, g * 8);
      cstats_stream<8, 1024, 16, 1><<<4096, 64, 0, stream>>>(
          buf2R, buf2I, coef, partial2g, g * 8);
      np_cov_combine3<8, 8, 64><<<1, 64, 0, stream>>>(partial2g, coef,
                                                      524288.f, g * 8);
      cpool_stream<8, 32, 32><<<512, 256, 0, stream>>>(
          buf2R, buf2I, coef, b2_grr, b2_gri, b2_gii, b2_br, b2_bi, P2r, P2i,
          g * 8);
    }
  } else {
    cconv_band_stats<32, 16, 32, 5, 0><<<4096, 128, 0, stream>>>(
        P1r, P1i, c2_wrT, c2_wiT, c2_br, c2_bi, coef, partial2);
    np_mean_combine3<32, 8, 64><<<1, 64, 0, stream>>>(partial2, coef,
                                                      524288.f, 0);
    cconv_band_stats<32, 16, 32, 5, 1><<<4096, 128, 0, stream>>>(
        P1r, P1i, c2_wrT, c2_wiT, c2_br, c2_bi, coef, partial2);
    np_cov_combine3<32, 8, 128><<<1, 128, 0, stream>>>(partial2, coef,
                                                       524288.f, 0);
    cconv_band_pool<32, 16, 32, 5, 2><<<4096, 128, 0, stream>>>(
        P1r, P1i, c2_wrT, c2_wiT, c2_br, c2_bi, coef, b2_grr, b2_gri, b2_gii,
        b2_br, b2_bi, P2r, P2i);
  }

  // ---- layer 3 (H=16, CIN=32, COUT=64, K=3, M=131072) — store-once, G=2,
  //      4-channel/thread store (256 threads, REPS=4; K=3 -> cheap w-reload)
  repack_w<<<72, 256, 0, stream>>>(c3_wr, c3_wrT, 32, 9, 18432);
  repack_w<<<72, 256, 0, stream>>>(c3_wi, c3_wiT, 32, 9, 18432);
  for (int g = 0; g < 2; ++g) {
    cconv_band_store4<16, 32, 64, 32, 3, 4><<<1024, 256, 0, stream>>>(
        P2r, P2i, c3_wrT, c3_wiT, c3_br, c3_bi, g * 32, buf3R, buf3I);
    cstats_stream<32, 256, 16, 0><<<1024, 256, 0, stream>>>(
        buf3R, buf3I, coef, partial3s, g * 32);
    np_mean_combine3<32, 2, 64><<<1, 64, 0, stream>>>(partial3s, coef,
                                                      131072.f, g * 32);
    cstats_stream<32, 256, 16, 1><<<1024, 256, 0, stream>>>(
        buf3R, buf3I, coef, partial3s, g * 32);
    np_cov_combine3<32, 2, 128><<<1, 128, 0, stream>>>(partial3s, coef,
                                                       131072.f, g * 32);
    cpool_stream<32, 16, 64><<<512, 256, 0, stream>>>(
        buf3R, buf3I, coef, b3_grr, b3_gri, b3_gii, b3_br, b3_bi, P3r, P3i,
        g * 32);
  }

  // ---- layer 4 (H=8, CIN=64, COUT=64, K=3, M=32768) — store-once, G=1,
  //      4-channel/thread store (256 threads, REPS=2)
  repack_w<<<144, 256, 0, stream>>>(c4_wr, c4_wrT, 64, 9, 36864);
  repack_w<<<144, 256, 0, stream>>>(c4_wi, c4_wiT, 64, 9, 36864);
  cconv_band_store4<8, 64, 64, 64, 3, 2><<<512, 256, 0, stream>>>(
      P3r, P3i, c4_wrT, c4_wiT, c4_br, c4_bi, 0, buf4R, buf4I);
  cstats_stream<64, 64, 8, 0><<<512, 512, 0, stream>>>(buf4R, buf4I, coef,
                                                       partialT, 0);
  np_mean_combine3<64, 1, 128><<<1, 128, 0, stream>>>(partialT, coef,
                                                      32768.f, 0);
  cstats_stream<64, 64, 8, 1><<<512, 512, 0, stream>>>(buf4R, buf4I, coef,
                                                       partialT, 0);
  np_cov_combine3<64, 1, 192><<<1, 192, 0, stream>>>(partialT, coef,
                                                     32768.f, 0);
  cpool_stream<64, 8, 64><<<512, 256, 0, stream>>>(
      buf4R, buf4I, coef, b4_grr, b4_gri, b4_gii, b4_br, b4_bi, P4r, P4i, 0);

  // ---- FC head (weights transposed into dead P1i region)
  transpose_rc<<<1024, 256, 0, stream>>>(fc1_wr, fc1_wrT, 256, 1024);
  transpose_rc<<<1024, 256, 0, stream>>>(fc1_wi, fc1_wiT, 256, 1024);
  transpose_rc<<<1000, 256, 0, stream>>>(fc2_w, fc2_wT, 1000, 256);
  fc_head_kernel<<<512, 256, 0, stream>>>(P4r, P4i, fc1_wrT, fc1_wiT, fc1_br,
                                          fc1_bi, fc2_wT, fc2_b, outL, er, ei);
}